// Round 1
// baseline (749.029 us; speedup 1.0000x reference)
//
#include <hip/hip_runtime.h>
#include <hip/hip_bf16.h>

typedef __bf16 bf16x8 __attribute__((ext_vector_type(8)));
typedef float f32x4 __attribute__((ext_vector_type(4)));
typedef unsigned short u16;
typedef unsigned int u32;

// Problem constants
#define B_   4
#define C_   128
#define K_   13
#define A_   12
#define P_   1024
#define D_   128
#define R_   12
// GEMM dims: M = R_*D_ = 1536, N = B_*P_ = 4096, K padded: 156 -> 160 per c
#define KT   20480   // 128 * 160
#define MT   1536
#define NT   4096

__device__ __forceinline__ u16 f2bf(float f) {
    u32 u = __builtin_bit_cast(u32, f);
    u32 r = (u + 0x7FFFu + ((u >> 16) & 1u)) >> 16;
    return (u16)r;
}

// ---------------------------------------------------------------------------
// pass1: x[b,c,k,p,a] f32  ->  Xb[n = b*1024+p][k_lin = c*160 + k*12 + a] bf16
// (pad columns 156..159 per c are zeroed)
// ---------------------------------------------------------------------------
__global__ __launch_bounds__(256) void pass1_xt(const float* __restrict__ x,
                                                u16* __restrict__ Xb) {
    __shared__ u16 lds[64 * 160];
    const int c  = blockIdx.y;
    const int b  = blockIdx.z;
    const int p0 = blockIdx.x * 64;
    const int t  = threadIdx.x;

    if (t < 64) {
        lds[t * 160 + 156] = 0;
        lds[t * 160 + 157] = 0;
        lds[t * 160 + 158] = 0;
        lds[t * 160 + 159] = 0;
    }
    const float* xbase = x + ((size_t)(b * C_ + c)) * (K_ * (size_t)P_ * A_) + (size_t)p0 * A_;
    if (t < 192) {
        for (int k = 0; k < K_; ++k) {
            const float4* src = (const float4*)(xbase + (size_t)k * (P_ * A_));
            float4 v = src[t];
            int e = t * 4;
            float fv[4] = {v.x, v.y, v.z, v.w};
#pragma unroll
            for (int j = 0; j < 4; ++j) {
                int ee = e + j;
                int pl = ee / 12;
                int a  = ee - pl * 12;
                lds[pl * 160 + k * 12 + a] = f2bf(fv[j]);
            }
        }
    }
    __syncthreads();
    const int n0 = b * P_ + p0;
    for (int pi = t; pi < 64 * 20; pi += 256) {
        int row = pi / 20;
        int pc  = pi % 20;
        uint4 v = *(const uint4*)&lds[row * 160 + pc * 8];
        *(uint4*)((char*)Xb + ((size_t)(n0 + row) * KT + c * 160 + pc * 8) * 2) = v;
    }
}

// ---------------------------------------------------------------------------
// pass2: Wb[m = r*128+d][k_lin] = bf16( W[d, c, kidx3[k,a,r], aidx3[k,a,r]] )
// ---------------------------------------------------------------------------
__global__ __launch_bounds__(256) void pass2_wb(const float* __restrict__ W,
                                                const int* __restrict__ kidx3,
                                                const int* __restrict__ aidx3,
                                                u16* __restrict__ Wb) {
    int t = blockIdx.x * 256 + threadIdx.x;   // 1536 * 2560 threads
    int k8 = t % (KT / 8);
    int m  = t / (KT / 8);
    int r  = m >> 7;
    int d  = m & 127;
    int kl0 = k8 * 8;
    int c   = kl0 / 160;
    int e0  = kl0 - c * 160;
    u16 vals[8];
#pragma unroll
    for (int j = 0; j < 8; ++j) {
        int e = e0 + j;
        u16 o = 0;
        if (e < 156) {
            int k = e / 12;
            int a = e - k * 12;
            int kk = kidx3[(k * 12 + a) * 12 + r];
            int aa = aidx3[(k * 12 + a) * 12 + r];
            o = f2bf(W[((d * C_ + c) * 5 + kk) * 12 + aa]);
        }
        vals[j] = o;
    }
    uint4 v;
    v.x = (u32)vals[0] | ((u32)vals[1] << 16);
    v.y = (u32)vals[2] | ((u32)vals[3] << 16);
    v.z = (u32)vals[4] | ((u32)vals[5] << 16);
    v.w = (u32)vals[6] | ((u32)vals[7] << 16);
    *(uint4*)((char*)Wb + ((size_t)m * KT + kl0) * 2) = v;
}

// ---------------------------------------------------------------------------
// gemm: Ct[m][n] = sum_k Wb[m][k] * Xb[n][k]   (both row-major bf16, K = KT)
// 128x128 tile, BK=64, 4 waves (2x2), mfma 16x16x32 bf16, global_load_lds w16
// ---------------------------------------------------------------------------
__global__ __launch_bounds__(256) void gemm128(const u16* __restrict__ A,
                                               const u16* __restrict__ Bt,
                                               float* __restrict__ C) {
    __shared__ u16 sA[128 * 64];
    __shared__ u16 sB[128 * 64];

    int bid = blockIdx.x;                       // 384 blocks, 384 % 8 == 0
    int swz = (bid & 7) * 48 + (bid >> 3);      // XCD-contiguous, bijective
    int mt = swz % 12;
    int nt = swz / 12;
    int m0 = mt * 128;
    int n0 = nt * 128;

    int tid  = threadIdx.x;
    int lane = tid & 63;
    int wid  = tid >> 6;
    int wm   = wid >> 1;
    int wn   = wid & 1;

    // staging: per issue i (0..3): rows i*32 + wid*8 + lane/8, 16B piece lane%8
    int srow = wid * 8 + (lane >> 3);
    int spc  = lane & 7;
    const u16* gA = A  + (size_t)(m0 + srow) * KT + spc * 8;
    const u16* gB = Bt + (size_t)(n0 + srow) * KT + spc * 8;

    f32x4 acc[4][4];
#pragma unroll
    for (int i = 0; i < 4; ++i)
#pragma unroll
        for (int j = 0; j < 4; ++j) acc[i][j] = (f32x4){0.f, 0.f, 0.f, 0.f};

    for (int kt = 0; kt < KT; kt += 64) {
#pragma unroll
        for (int i = 0; i < 4; ++i) {
            __builtin_amdgcn_global_load_lds(
                (const __attribute__((address_space(1))) void*)(gA + (size_t)i * 32 * KT + kt),
                (__attribute__((address_space(3))) void*)&sA[(i * 32 + wid * 8) * 64],
                16, 0, 0);
            __builtin_amdgcn_global_load_lds(
                (const __attribute__((address_space(1))) void*)(gB + (size_t)i * 32 * KT + kt),
                (__attribute__((address_space(3))) void*)&sB[(i * 32 + wid * 8) * 64],
                16, 0, 0);
        }
        __syncthreads();
#pragma unroll
        for (int ks = 0; ks < 2; ++ks) {
            bf16x8 af[4], bfr[4];
#pragma unroll
            for (int mf = 0; mf < 4; ++mf)
                af[mf] = *(const bf16x8*)&sA[(wm * 64 + mf * 16 + (lane & 15)) * 64 + ks * 32 + (lane >> 4) * 8];
#pragma unroll
            for (int nf = 0; nf < 4; ++nf)
                bfr[nf] = *(const bf16x8*)&sB[(wn * 64 + nf * 16 + (lane & 15)) * 64 + ks * 32 + (lane >> 4) * 8];
#pragma unroll
            for (int mf = 0; mf < 4; ++mf)
#pragma unroll
                for (int nf = 0; nf < 4; ++nf)
                    acc[mf][nf] = __builtin_amdgcn_mfma_f32_16x16x32_bf16(
                        af[mf], bfr[nf], acc[mf][nf], 0, 0, 0);
        }
        __syncthreads();
    }

    int row0 = m0 + wm * 64 + (lane >> 4) * 4;
    int col0 = n0 + wn * 64 + (lane & 15);
#pragma unroll
    for (int mf = 0; mf < 4; ++mf)
#pragma unroll
        for (int nf = 0; nf < 4; ++nf) {
            int rr = row0 + mf * 16;
            int cc = col0 + nf * 16;
#pragma unroll
            for (int v = 0; v < 4; ++v)
                C[(size_t)(rr + v) * NT + cc] = acc[mf][nf][v];
        }
}

// ---------------------------------------------------------------------------
// pass4: out[b,d,p,r] = Ct[r*128 + d][b*1024 + p]   (contiguous (p,r) writes)
// ---------------------------------------------------------------------------
__global__ __launch_bounds__(256) void pass4_out(const float* __restrict__ Ct,
                                                 float* __restrict__ out) {
    __shared__ float lds[12 * 256];
    int bid = blockIdx.x;
    int pch = bid & 3;
    int d   = (bid >> 2) & 127;
    int b   = bid >> 9;
    int p0  = pch * 256;
    int t   = threadIdx.x;
#pragma unroll
    for (int r = 0; r < 12; ++r)
        lds[r * 256 + t] = Ct[(size_t)(r * D_ + d) * NT + b * P_ + p0 + t];
    __syncthreads();
    float* obase = out + ((size_t)((b * D_ + d) * P_ + p0)) * 12;
#pragma unroll
    for (int q = 0; q < 3; ++q) {
        int e0 = q * 1024 + t * 4;
        float4 v;
        {
            int e = e0 + 0; int p = e / 12; int r = e - p * 12; v.x = lds[r * 256 + p];
        }
        {
            int e = e0 + 1; int p = e / 12; int r = e - p * 12; v.y = lds[r * 256 + p];
        }
        {
            int e = e0 + 2; int p = e / 12; int r = e - p * 12; v.z = lds[r * 256 + p];
        }
        {
            int e = e0 + 3; int p = e / 12; int r = e - p * 12; v.w = lds[r * 256 + p];
        }
        *(float4*)(obase + e0) = v;
    }
}

// ---------------------------------------------------------------------------
// fallback (only if ws_size is too small): direct naive computation
// ---------------------------------------------------------------------------
__global__ __launch_bounds__(256) void naive_kernel(const float* __restrict__ x,
                                                    const float* __restrict__ W,
                                                    const int* __restrict__ kidx3,
                                                    const int* __restrict__ aidx3,
                                                    float* __restrict__ out) {
    long long t = (long long)blockIdx.x * 256 + threadIdx.x;
    if (t >= (long long)B_ * D_ * P_ * R_) return;
    int r = (int)(t % 12);
    int p = (int)((t / 12) % P_);
    int d = (int)((t / (12 * P_)) % D_);
    int b = (int)(t / (12 * (long long)P_ * D_));
    int kk[K_];
    int aa[A_];
#pragma unroll
    for (int k = 0; k < K_; ++k) kk[k] = kidx3[(k * 12 + 0) * 12 + r];
#pragma unroll
    for (int a = 0; a < A_; ++a) aa[a] = aidx3[(0 * 12 + a) * 12 + r];
    float sum = 0.f;
    for (int c = 0; c < C_; ++c) {
        const float* wrow = W + (size_t)(d * C_ + c) * 60;
        const float* xrow = x + ((size_t)(b * C_ + c) * K_) * (P_ * A_) + (size_t)p * A_;
        for (int k = 0; k < K_; ++k) {
            const float* wk = wrow + kk[k] * 12;
            const float* xk = xrow + (size_t)k * (P_ * A_);
#pragma unroll
            for (int a = 0; a < A_; ++a) sum += wk[aa[a]] * xk[a];
        }
    }
    out[t] = sum;
}

extern "C" void kernel_launch(void* const* d_in, const int* in_sizes, int n_in,
                              void* d_out, int out_size, void* d_ws, size_t ws_size,
                              hipStream_t stream) {
    const float* x     = (const float*)d_in[0];
    const float* W     = (const float*)d_in[1];
    const int*   kidx3 = (const int*)d_in[2];
    const int*   aidx3 = (const int*)d_in[3];
    float*       out   = (float*)d_out;

    const size_t XB = (size_t)NT * KT * 2;   // 167,772,160
    const size_t WB = (size_t)MT * KT * 2;   //  62,914,560
    const size_t CT = (size_t)MT * NT * 4;   //  25,165,824

    if (ws_size >= XB + WB + CT) {
        u16*   Xb = (u16*)d_ws;
        u16*   Wb = (u16*)((char*)d_ws + XB);
        float* Ct = (float*)((char*)d_ws + XB + WB);
        pass1_xt<<<dim3(16, 128, 4), 256, 0, stream>>>(x, Xb);
        pass2_wb<<<(MT * (KT / 8)) / 256, 256, 0, stream>>>(W, kidx3, aidx3, Wb);
        gemm128<<<384, 256, 0, stream>>>(Wb, Xb, Ct);
        pass4_out<<<2048, 256, 0, stream>>>(Ct, out);
    } else {
        naive_kernel<<<(B_ * D_ * P_ * R_) / 256, 256, 0, stream>>>(x, W, kidx3, aidx3, out);
    }
}

// Round 2
// 645.356 us; speedup vs baseline: 1.1606x; 1.1606x over previous
//
#include <hip/hip_runtime.h>
#include <hip/hip_bf16.h>

typedef __bf16 bf16x8 __attribute__((ext_vector_type(8)));
typedef float f32x4 __attribute__((ext_vector_type(4)));
typedef unsigned short u16;
typedef unsigned int u32;

// Problem constants
#define B_   4
#define C_   128
#define K_   13
#define A_   12
#define P_   1024
#define D_   128
#define R_   12
// GEMM dims: M = R_*D_ = 1536, N = B_*P_ = 4096, K padded: 156 -> 160 per c
#define KT   20480   // 128 * 160
#define MT   1536
#define NT   4096

__device__ __forceinline__ u16 f2bf(float f) {
    u32 u = __builtin_bit_cast(u32, f);
    u32 r = (u + 0x7FFFu + ((u >> 16) & 1u)) >> 16;
    return (u16)r;
}

// ---------------------------------------------------------------------------
// pass1: x[b,c,k,p,a] f32  ->  Xb[n = b*1024+p][k_lin = c*160 + k*12 + a] bf16
// (pad columns 156..159 per c are zeroed)
// ---------------------------------------------------------------------------
__global__ __launch_bounds__(256) void pass1_xt(const float* __restrict__ x,
                                                u16* __restrict__ Xb) {
    __shared__ u16 lds[64 * 160];
    const int c  = blockIdx.y;
    const int b  = blockIdx.z;
    const int p0 = blockIdx.x * 64;
    const int t  = threadIdx.x;

    if (t < 64) {
        lds[t * 160 + 156] = 0;
        lds[t * 160 + 157] = 0;
        lds[t * 160 + 158] = 0;
        lds[t * 160 + 159] = 0;
    }
    const float* xbase = x + ((size_t)(b * C_ + c)) * (K_ * (size_t)P_ * A_) + (size_t)p0 * A_;
    if (t < 192) {
        for (int k = 0; k < K_; ++k) {
            const float4* src = (const float4*)(xbase + (size_t)k * (P_ * A_));
            float4 v = src[t];
            int e = t * 4;
            float fv[4] = {v.x, v.y, v.z, v.w};
#pragma unroll
            for (int j = 0; j < 4; ++j) {
                int ee = e + j;
                int pl = ee / 12;
                int a  = ee - pl * 12;
                lds[pl * 160 + k * 12 + a] = f2bf(fv[j]);
            }
        }
    }
    __syncthreads();
    const int n0 = b * P_ + p0;
    for (int pi = t; pi < 64 * 20; pi += 256) {
        int row = pi / 20;
        int pc  = pi % 20;
        uint4 v = *(const uint4*)&lds[row * 160 + pc * 8];
        *(uint4*)((char*)Xb + ((size_t)(n0 + row) * KT + c * 160 + pc * 8) * 2) = v;
    }
}

// ---------------------------------------------------------------------------
// pass2: Wb[m = r*128+d][k_lin] = bf16( W[d, c, kidx3[k,a,r], aidx3[k,a,r]] )
// ---------------------------------------------------------------------------
__global__ __launch_bounds__(256) void pass2_wb(const float* __restrict__ W,
                                                const int* __restrict__ kidx3,
                                                const int* __restrict__ aidx3,
                                                u16* __restrict__ Wb) {
    int t = blockIdx.x * 256 + threadIdx.x;   // 1536 * 2560 threads
    int k8 = t % (KT / 8);
    int m  = t / (KT / 8);
    int r  = m >> 7;
    int d  = m & 127;
    int kl0 = k8 * 8;
    int c   = kl0 / 160;
    int e0  = kl0 - c * 160;
    u16 vals[8];
#pragma unroll
    for (int j = 0; j < 8; ++j) {
        int e = e0 + j;
        u16 o = 0;
        if (e < 156) {
            int k = e / 12;
            int a = e - k * 12;
            int kk = kidx3[(k * 12 + a) * 12 + r];
            int aa = aidx3[(k * 12 + a) * 12 + r];
            o = f2bf(W[((d * C_ + c) * 5 + kk) * 12 + aa]);
        }
        vals[j] = o;
    }
    uint4 v;
    v.x = (u32)vals[0] | ((u32)vals[1] << 16);
    v.y = (u32)vals[2] | ((u32)vals[3] << 16);
    v.z = (u32)vals[4] | ((u32)vals[5] << 16);
    v.w = (u32)vals[6] | ((u32)vals[7] << 16);
    *(uint4*)((char*)Wb + ((size_t)m * KT + kl0) * 2) = v;
}

// ---------------------------------------------------------------------------
// gemm: Ct[s][m][n] = sum_{k in chunk s} Wb[m][k] * Xb[n][k]
// 128x128 tile, BK=64, 4 waves (2x2), mfma 16x16x32 bf16, global_load_lds w16
// split-K: blockIdx.y = chunk index (KT/SPLIT each), partials to disjoint slabs
// ---------------------------------------------------------------------------
template <int SPLIT>
__global__ __launch_bounds__(256) void gemm128(const u16* __restrict__ A,
                                               const u16* __restrict__ Bt,
                                               float* __restrict__ C) {
    __shared__ u16 sA[128 * 64];
    __shared__ u16 sB[128 * 64];

    int bid = blockIdx.x;                       // 384 blocks, 384 % 8 == 0
    int swz = (bid & 7) * 48 + (bid >> 3);      // XCD-contiguous, bijective
    int mt = swz % 12;
    int nt = swz / 12;
    int m0 = mt * 128;
    int n0 = nt * 128;
    int ks0 = blockIdx.y * (KT / SPLIT);

    int tid  = threadIdx.x;
    int lane = tid & 63;
    int wid  = tid >> 6;
    int wm   = wid >> 1;
    int wn   = wid & 1;

    // staging: per issue i (0..3): rows i*32 + wid*8 + lane/8, 16B piece lane%8
    int srow = wid * 8 + (lane >> 3);
    int spc  = lane & 7;
    const u16* gA = A  + (size_t)(m0 + srow) * KT + spc * 8;
    const u16* gB = Bt + (size_t)(n0 + srow) * KT + spc * 8;

    f32x4 acc[4][4];
#pragma unroll
    for (int i = 0; i < 4; ++i)
#pragma unroll
        for (int j = 0; j < 4; ++j) acc[i][j] = (f32x4){0.f, 0.f, 0.f, 0.f};

    for (int kt = ks0; kt < ks0 + KT / SPLIT; kt += 64) {
#pragma unroll
        for (int i = 0; i < 4; ++i) {
            __builtin_amdgcn_global_load_lds(
                (const __attribute__((address_space(1))) void*)(gA + (size_t)i * 32 * KT + kt),
                (__attribute__((address_space(3))) void*)&sA[(i * 32 + wid * 8) * 64],
                16, 0, 0);
            __builtin_amdgcn_global_load_lds(
                (const __attribute__((address_space(1))) void*)(gB + (size_t)i * 32 * KT + kt),
                (__attribute__((address_space(3))) void*)&sB[(i * 32 + wid * 8) * 64],
                16, 0, 0);
        }
        __syncthreads();
#pragma unroll
        for (int ks = 0; ks < 2; ++ks) {
            bf16x8 af[4], bfr[4];
#pragma unroll
            for (int mf = 0; mf < 4; ++mf)
                af[mf] = *(const bf16x8*)&sA[(wm * 64 + mf * 16 + (lane & 15)) * 64 + ks * 32 + (lane >> 4) * 8];
#pragma unroll
            for (int nf = 0; nf < 4; ++nf)
                bfr[nf] = *(const bf16x8*)&sB[(wn * 64 + nf * 16 + (lane & 15)) * 64 + ks * 32 + (lane >> 4) * 8];
#pragma unroll
            for (int mf = 0; mf < 4; ++mf)
#pragma unroll
                for (int nf = 0; nf < 4; ++nf)
                    acc[mf][nf] = __builtin_amdgcn_mfma_f32_16x16x32_bf16(
                        af[mf], bfr[nf], acc[mf][nf], 0, 0, 0);
        }
        __syncthreads();
    }

    float* Cs = C + (size_t)blockIdx.y * MT * NT;
    int row0 = m0 + wm * 64 + (lane >> 4) * 4;
    int col0 = n0 + wn * 64 + (lane & 15);
#pragma unroll
    for (int mf = 0; mf < 4; ++mf)
#pragma unroll
        for (int nf = 0; nf < 4; ++nf) {
            int rr = row0 + mf * 16;
            int cc = col0 + nf * 16;
#pragma unroll
            for (int v = 0; v < 4; ++v)
                Cs[(size_t)(rr + v) * NT + cc] = acc[mf][nf][v];
        }
}

// ---------------------------------------------------------------------------
// pass4: out[b,d,p,r] = sum_s Ct[s][r*128 + d][b*1024 + p]  (contig (p,r) writes)
// ---------------------------------------------------------------------------
template <int SPLIT>
__global__ __launch_bounds__(256) void pass4_out(const float* __restrict__ Ct,
                                                 float* __restrict__ out) {
    __shared__ float lds[12 * 256];
    int bid = blockIdx.x;
    int pch = bid & 3;
    int d   = (bid >> 2) & 127;
    int b   = bid >> 9;
    int p0  = pch * 256;
    int t   = threadIdx.x;
#pragma unroll
    for (int r = 0; r < 12; ++r) {
        size_t off = (size_t)(r * D_ + d) * NT + b * P_ + p0 + t;
        float s = 0.f;
#pragma unroll
        for (int sp = 0; sp < SPLIT; ++sp)
            s += Ct[(size_t)sp * MT * NT + off];
        lds[r * 256 + t] = s;
    }
    __syncthreads();
    float* obase = out + ((size_t)((b * D_ + d) * P_ + p0)) * 12;
#pragma unroll
    for (int q = 0; q < 3; ++q) {
        int e0 = q * 1024 + t * 4;
        float4 v;
        {
            int e = e0 + 0; int p = e / 12; int r = e - p * 12; v.x = lds[r * 256 + p];
        }
        {
            int e = e0 + 1; int p = e / 12; int r = e - p * 12; v.y = lds[r * 256 + p];
        }
        {
            int e = e0 + 2; int p = e / 12; int r = e - p * 12; v.z = lds[r * 256 + p];
        }
        {
            int e = e0 + 3; int p = e / 12; int r = e - p * 12; v.w = lds[r * 256 + p];
        }
        *(float4*)(obase + e0) = v;
    }
}

// ---------------------------------------------------------------------------
// fallback (only if ws_size is too small): direct naive computation
// ---------------------------------------------------------------------------
__global__ __launch_bounds__(256) void naive_kernel(const float* __restrict__ x,
                                                    const float* __restrict__ W,
                                                    const int* __restrict__ kidx3,
                                                    const int* __restrict__ aidx3,
                                                    float* __restrict__ out) {
    long long t = (long long)blockIdx.x * 256 + threadIdx.x;
    if (t >= (long long)B_ * D_ * P_ * R_) return;
    int r = (int)(t % 12);
    int p = (int)((t / 12) % P_);
    int d = (int)((t / (12 * P_)) % D_);
    int b = (int)(t / (12 * (long long)P_ * D_));
    int kk[K_];
    int aa[A_];
#pragma unroll
    for (int k = 0; k < K_; ++k) kk[k] = kidx3[(k * 12 + 0) * 12 + r];
#pragma unroll
    for (int a = 0; a < A_; ++a) aa[a] = aidx3[(0 * 12 + a) * 12 + r];
    float sum = 0.f;
    for (int c = 0; c < C_; ++c) {
        const float* wrow = W + (size_t)(d * C_ + c) * 60;
        const float* xrow = x + ((size_t)(b * C_ + c) * K_) * (P_ * A_) + (size_t)p * A_;
        for (int k = 0; k < K_; ++k) {
            const float* wk = wrow + kk[k] * 12;
            const float* xk = xrow + (size_t)k * (P_ * A_);
#pragma unroll
            for (int a = 0; a < A_; ++a) sum += wk[aa[a]] * xk[a];
        }
    }
    out[t] = sum;
}

extern "C" void kernel_launch(void* const* d_in, const int* in_sizes, int n_in,
                              void* d_out, int out_size, void* d_ws, size_t ws_size,
                              hipStream_t stream) {
    const float* x     = (const float*)d_in[0];
    const float* W     = (const float*)d_in[1];
    const int*   kidx3 = (const int*)d_in[2];
    const int*   aidx3 = (const int*)d_in[3];
    float*       out   = (float*)d_out;

    const size_t XB = (size_t)NT * KT * 2;   // 167,772,160
    const size_t WB = (size_t)MT * KT * 2;   //  62,914,560
    const size_t CT = (size_t)MT * NT * 4;   //  25,165,824

    if (ws_size >= XB + WB + 4 * CT) {
        // split-K x4: 1536 blocks -> ~5 blocks/CU resident (occupancy fix)
        u16*   Xb = (u16*)d_ws;
        u16*   Wb = (u16*)((char*)d_ws + XB);
        float* Ct = (float*)((char*)d_ws + XB + WB);
        pass1_xt<<<dim3(16, 128, 4), 256, 0, stream>>>(x, Xb);
        pass2_wb<<<(MT * (KT / 8)) / 256, 256, 0, stream>>>(W, kidx3, aidx3, Wb);
        gemm128<4><<<dim3(384, 4), 256, 0, stream>>>(Wb, Xb, Ct);
        pass4_out<4><<<2048, 256, 0, stream>>>(Ct, out);
    } else if (ws_size >= XB + WB + CT) {
        u16*   Xb = (u16*)d_ws;
        u16*   Wb = (u16*)((char*)d_ws + XB);
        float* Ct = (float*)((char*)d_ws + XB + WB);
        pass1_xt<<<dim3(16, 128, 4), 256, 0, stream>>>(x, Xb);
        pass2_wb<<<(MT * (KT / 8)) / 256, 256, 0, stream>>>(W, kidx3, aidx3, Wb);
        gemm128<1><<<dim3(384, 1), 256, 0, stream>>>(Wb, Xb, Ct);
        pass4_out<1><<<2048, 256, 0, stream>>>(Ct, out);
    } else {
        naive_kernel<<<(B_ * D_ * P_ * R_) / 256, 256, 0, stream>>>(x, W, kidx3, aidx3, out);
    }
}

// Round 3
// 617.433 us; speedup vs baseline: 1.2131x; 1.0452x over previous
//
#include <hip/hip_runtime.h>
#include <hip/hip_bf16.h>

typedef __bf16 bf16x8 __attribute__((ext_vector_type(8)));
typedef float f32x4 __attribute__((ext_vector_type(4)));
typedef unsigned short u16;
typedef unsigned int u32;

// Problem constants
#define B_   4
#define C_   128
#define K_   13
#define A_   12
#define P_   1024
#define D_   128
#define R_   12
// GEMM dims: M = R_*D_ = 1536, N = B_*P_ = 4096, K padded: 156 -> 160 per c
#define KT   20480   // 128 * 160
#define MT   1536
#define NT   4096

__device__ __forceinline__ u16 f2bf(float f) {
    u32 u = __builtin_bit_cast(u32, f);
    u32 r = (u + 0x7FFFu + ((u >> 16) & 1u)) >> 16;
    return (u16)r;
}
__device__ __forceinline__ float bf2f(u16 v) {
    u32 u = (u32)v << 16;
    return __builtin_bit_cast(float, u);
}

__device__ __forceinline__ void barrier_() {
    asm volatile("" ::: "memory");
    __builtin_amdgcn_s_barrier();
    asm volatile("" ::: "memory");
}
__device__ __forceinline__ void lgkm0_() {
    asm volatile("s_waitcnt lgkmcnt(0)" ::: "memory");
    __builtin_amdgcn_sched_barrier(0);
}

// ---------------------------------------------------------------------------
// pass1: x[b,c,k,p,a] f32  ->  Xb[n = b*1024+p][k_lin = c*160 + k*12 + a] bf16
// ---------------------------------------------------------------------------
__global__ __launch_bounds__(256) void pass1_xt(const float* __restrict__ x,
                                                u16* __restrict__ Xb) {
    __shared__ u16 lds[64 * 160];
    const int c  = blockIdx.y;
    const int b  = blockIdx.z;
    const int p0 = blockIdx.x * 64;
    const int t  = threadIdx.x;

    if (t < 64) {
        lds[t * 160 + 156] = 0;
        lds[t * 160 + 157] = 0;
        lds[t * 160 + 158] = 0;
        lds[t * 160 + 159] = 0;
    }
    const float* xbase = x + ((size_t)(b * C_ + c)) * (K_ * (size_t)P_ * A_) + (size_t)p0 * A_;
    if (t < 192) {
        for (int k = 0; k < K_; ++k) {
            const float4* src = (const float4*)(xbase + (size_t)k * (P_ * A_));
            float4 v = src[t];
            int e = t * 4;
            float fv[4] = {v.x, v.y, v.z, v.w};
#pragma unroll
            for (int j = 0; j < 4; ++j) {
                int ee = e + j;
                int pl = ee / 12;
                int a  = ee - pl * 12;
                lds[pl * 160 + k * 12 + a] = f2bf(fv[j]);
            }
        }
    }
    __syncthreads();
    const int n0 = b * P_ + p0;
    for (int pi = t; pi < 64 * 20; pi += 256) {
        int row = pi / 20;
        int pc  = pi % 20;
        uint4 v = *(const uint4*)&lds[row * 160 + pc * 8];
        *(uint4*)((char*)Xb + ((size_t)(n0 + row) * KT + c * 160 + pc * 8) * 2) = v;
    }
}

// ---------------------------------------------------------------------------
// pass2: Wb[m = r*128+d][k_lin] = bf16( W[d, c, kidx3[k,a,r], aidx3[k,a,r]] )
// ---------------------------------------------------------------------------
__global__ __launch_bounds__(256) void pass2_wb(const float* __restrict__ W,
                                                const int* __restrict__ kidx3,
                                                const int* __restrict__ aidx3,
                                                u16* __restrict__ Wb) {
    int t = blockIdx.x * 256 + threadIdx.x;
    int k8 = t % (KT / 8);
    int m  = t / (KT / 8);
    int r  = m >> 7;
    int d  = m & 127;
    int kl0 = k8 * 8;
    int c   = kl0 / 160;
    int e0  = kl0 - c * 160;
    u16 vals[8];
#pragma unroll
    for (int j = 0; j < 8; ++j) {
        int e = e0 + j;
        u16 o = 0;
        if (e < 156) {
            int k = e / 12;
            int a = e - k * 12;
            int kk = kidx3[(k * 12 + a) * 12 + r];
            int aa = aidx3[(k * 12 + a) * 12 + r];
            o = f2bf(W[((d * C_ + c) * 5 + kk) * 12 + aa]);
        }
        vals[j] = o;
    }
    uint4 v;
    v.x = (u32)vals[0] | ((u32)vals[1] << 16);
    v.y = (u32)vals[2] | ((u32)vals[3] << 16);
    v.z = (u32)vals[4] | ((u32)vals[5] << 16);
    v.w = (u32)vals[6] | ((u32)vals[7] << 16);
    *(uint4*)((char*)Wb + ((size_t)m * KT + kl0) * 2) = v;
}

// ---------------------------------------------------------------------------
// gemm256: 8-phase 256x256 tile, BK=64, 8 waves (2M x 4N), dbuf LDS, T2
// swizzle (chunk ^= row&7 on read; inverse pre-swizzle on global src of
// global_load_lds), counted vmcnt(6) once per K-tile, setprio around MFMA.
// Split-K: blockIdx.y picks a KT/SPLIT chunk; partials -> slab blockIdx.y.
// Staging ledger (tile u reads buf[u&1]):
//   u.ph0: issue A-half1(u+1)    -> buf[~u]  (safe: tile u-1 reads done)
//   u.ph2: issue B-half0(u+2)    -> buf[u]   (B-reads of u done end ph1)
//   u.ph3: issue B-half1 + A-half0 (u+2)     (A-reads of u done end ph2)
//   u.ph3: s_waitcnt vmcnt(6)  => tile u+1's 4 halves (8 loads) landed,
//          3 half-tiles (6 loads) of u+2 stay in flight across the barrier.
// ---------------------------------------------------------------------------
template <int SPLIT, typename CTYPE>
__global__ __launch_bounds__(512, 2) void gemm256(const u16* __restrict__ A,
                                                  const u16* __restrict__ Bt,
                                                  CTYPE* __restrict__ C) {
    __shared__ u16 sA[2][256 * 64];
    __shared__ u16 sB[2][256 * 64];

    const int NTL = (KT / SPLIT) / 64;          // K-tiles per block (40)
    int bid = blockIdx.x;                        // 96 tiles, 96 % 8 == 0
    int swz = (bid & 7) * 12 + (bid >> 3);       // XCD-contiguous, bijective
    int m0 = (swz % 6) * 256;
    int n0 = (swz / 6) * 256;
    int ks0 = blockIdx.y * (KT / SPLIT);

    int tid  = threadIdx.x;
    int lane = tid & 63;
    int wid  = tid >> 6;
    int wm   = wid >> 2;                         // 0..1
    int wn   = wid & 3;                          // 0..3

    // per-lane pre-swizzled global source (linear LDS dest, rule #21)
    int schunk = (lane & 7) ^ (lane >> 3);
    const u16* gA = A  + (size_t)(m0 + wid * 16 + (lane >> 3)) * KT + ks0 + schunk * 8;
    const u16* gB = Bt + (size_t)(n0 + wid * 16 + (lane >> 3)) * KT + ks0 + schunk * 8;

    auto stA = [&](int buf, int t_, int h) {
#pragma unroll
        for (int i = 0; i < 2; ++i)
            __builtin_amdgcn_global_load_lds(
                (const __attribute__((address_space(1))) void*)(gA + (size_t)(h * 128 + i * 8) * KT + (size_t)t_ * 64),
                (__attribute__((address_space(3))) void*)&sA[buf][(h * 128 + wid * 16 + i * 8) * 64],
                16, 0, 0);
    };
    auto stB = [&](int buf, int t_, int h) {
#pragma unroll
        for (int i = 0; i < 2; ++i)
            __builtin_amdgcn_global_load_lds(
                (const __attribute__((address_space(1))) void*)(gB + (size_t)(h * 128 + i * 8) * KT + (size_t)t_ * 64),
                (__attribute__((address_space(3))) void*)&sB[buf][(h * 128 + wid * 16 + i * 8) * 64],
                16, 0, 0);
    };
    auto ldA = [&](int buf, int row, int ks) -> bf16x8 {
        int chunk = ((ks << 2) + (lane >> 4)) ^ (row & 7);
        return *(const bf16x8*)&sA[buf][row * 64 + chunk * 8];
    };
    auto ldB = [&](int buf, int row, int ks) -> bf16x8 {
        int chunk = ((ks << 2) + (lane >> 4)) ^ (row & 7);
        return *(const bf16x8*)&sB[buf][row * 64 + chunk * 8];
    };

    f32x4 acc[8][4];
#pragma unroll
    for (int i = 0; i < 8; ++i)
#pragma unroll
        for (int j = 0; j < 4; ++j) acc[i][j] = (f32x4){0.f, 0.f, 0.f, 0.f};

    // prologue: tile0 fully (B0,B1,A0,A1 -> buf0), tile1's B0,B1,A0 -> buf1
    stB(0, 0, 0); stB(0, 0, 1); stA(0, 0, 0); stA(0, 0, 1);
    stB(1, 1, 0); stB(1, 1, 1); stA(1, 1, 0);
    asm volatile("s_waitcnt vmcnt(6)" ::: "memory");   // tile0's 8 loads landed
    barrier_();

    bf16x8 af[4][2], bfr[4][2];

    for (int u = 0; u < NTL; ++u) {
        int cur = u & 1;
        int rB = wn * 64 + (lane & 15);
        int rA = wm * 128 + (lane & 15);

        // ---------------- phase 0: B nf0-1, A mf0-3; MFMA Q(mf0-3,nf0-1)
#pragma unroll
        for (int nf = 0; nf < 2; ++nf)
#pragma unroll
            for (int ks = 0; ks < 2; ++ks)
                bfr[nf][ks] = ldB(cur, rB + nf * 16, ks);
#pragma unroll
        for (int mf = 0; mf < 4; ++mf)
#pragma unroll
            for (int ks = 0; ks < 2; ++ks)
                af[mf][ks] = ldA(cur, rA + mf * 16, ks);
        if (u + 1 < NTL) stA(cur ^ 1, u + 1, 1);       // A-half1(u+1)
        barrier_();
        lgkm0_();
        __builtin_amdgcn_s_setprio(1);
#pragma unroll
        for (int mf = 0; mf < 4; ++mf)
#pragma unroll
            for (int nf = 0; nf < 2; ++nf)
#pragma unroll
                for (int ks = 0; ks < 2; ++ks)
                    acc[mf][nf] = __builtin_amdgcn_mfma_f32_16x16x32_bf16(
                        af[mf][ks], bfr[nf][ks], acc[mf][nf], 0, 0, 0);
        __builtin_amdgcn_s_setprio(0);
        barrier_();

        // ---------------- phase 1: B nf2-3; MFMA Q(mf0-3,nf2-3)
#pragma unroll
        for (int nf = 2; nf < 4; ++nf)
#pragma unroll
            for (int ks = 0; ks < 2; ++ks)
                bfr[nf][ks] = ldB(cur, rB + nf * 16, ks);
        barrier_();
        lgkm0_();
        __builtin_amdgcn_s_setprio(1);
#pragma unroll
        for (int mf = 0; mf < 4; ++mf)
#pragma unroll
            for (int nf = 2; nf < 4; ++nf)
#pragma unroll
                for (int ks = 0; ks < 2; ++ks)
                    acc[mf][nf] = __builtin_amdgcn_mfma_f32_16x16x32_bf16(
                        af[mf][ks], bfr[nf][ks], acc[mf][nf], 0, 0, 0);
        __builtin_amdgcn_s_setprio(0);
        barrier_();

        // ---------------- phase 2: A mf4-7; MFMA Q(mf4-7,nf0-1)
#pragma unroll
        for (int mf = 0; mf < 4; ++mf)
#pragma unroll
            for (int ks = 0; ks < 2; ++ks)
                af[mf][ks] = ldA(cur, rA + (mf + 4) * 16, ks);
        if (u + 2 < NTL) stB(cur, u + 2, 0);           // B-half0(u+2)
        barrier_();
        lgkm0_();
        __builtin_amdgcn_s_setprio(1);
#pragma unroll
        for (int mf = 0; mf < 4; ++mf)
#pragma unroll
            for (int nf = 0; nf < 2; ++nf)
#pragma unroll
                for (int ks = 0; ks < 2; ++ks)
                    acc[mf + 4][nf] = __builtin_amdgcn_mfma_f32_16x16x32_bf16(
                        af[mf][ks], bfr[nf][ks], acc[mf + 4][nf], 0, 0, 0);
        __builtin_amdgcn_s_setprio(0);
        barrier_();

        // ---------------- phase 3: MFMA Q(mf4-7,nf2-3); counted vmcnt
        if (u + 2 < NTL) { stB(cur, u + 2, 1); stA(cur, u + 2, 0); }
        barrier_();
        lgkm0_();
        __builtin_amdgcn_s_setprio(1);
#pragma unroll
        for (int mf = 0; mf < 4; ++mf)
#pragma unroll
            for (int nf = 2; nf < 4; ++nf)
#pragma unroll
                for (int ks = 0; ks < 2; ++ks)
                    acc[mf + 4][nf] = __builtin_amdgcn_mfma_f32_16x16x32_bf16(
                        af[mf][ks], bfr[nf][ks], acc[mf + 4][nf], 0, 0, 0);
        __builtin_amdgcn_s_setprio(0);
        if (u + 2 < NTL) asm volatile("s_waitcnt vmcnt(6)" ::: "memory");
        else             asm volatile("s_waitcnt vmcnt(0)" ::: "memory");
        barrier_();
    }

    // epilogue: store partial tile to slab blockIdx.y
    CTYPE* Cs = C + (size_t)blockIdx.y * ((size_t)MT * NT);
    int r0 = m0 + wm * 128 + ((lane >> 4) << 2);
    int c0 = n0 + wn * 64 + (lane & 15);
#pragma unroll
    for (int mf = 0; mf < 8; ++mf)
#pragma unroll
        for (int nf = 0; nf < 4; ++nf)
#pragma unroll
            for (int v = 0; v < 4; ++v) {
                size_t idx = (size_t)(r0 + mf * 16 + v) * NT + (c0 + nf * 16);
                if constexpr (sizeof(CTYPE) == 2) Cs[idx] = f2bf(acc[mf][nf][v]);
                else                              Cs[idx] = acc[mf][nf][v];
            }
}

// ---------------------------------------------------------------------------
// gemm128 (R2 fallback): 128x128 tile, 2-barrier loop
// ---------------------------------------------------------------------------
template <int SPLIT>
__global__ __launch_bounds__(256) void gemm128(const u16* __restrict__ A,
                                               const u16* __restrict__ Bt,
                                               float* __restrict__ C) {
    __shared__ u16 sA[128 * 64];
    __shared__ u16 sB[128 * 64];

    int bid = blockIdx.x;
    int swz = (bid & 7) * 48 + (bid >> 3);
    int mt = swz % 12;
    int nt = swz / 12;
    int m0 = mt * 128;
    int n0 = nt * 128;
    int ks0 = blockIdx.y * (KT / SPLIT);

    int tid  = threadIdx.x;
    int lane = tid & 63;
    int wid  = tid >> 6;
    int wm   = wid >> 1;
    int wn   = wid & 1;

    int srow = wid * 8 + (lane >> 3);
    int spc  = lane & 7;
    const u16* gA = A  + (size_t)(m0 + srow) * KT + spc * 8;
    const u16* gB = Bt + (size_t)(n0 + srow) * KT + spc * 8;

    f32x4 acc[4][4];
#pragma unroll
    for (int i = 0; i < 4; ++i)
#pragma unroll
        for (int j = 0; j < 4; ++j) acc[i][j] = (f32x4){0.f, 0.f, 0.f, 0.f};

    for (int kt = ks0; kt < ks0 + KT / SPLIT; kt += 64) {
#pragma unroll
        for (int i = 0; i < 4; ++i) {
            __builtin_amdgcn_global_load_lds(
                (const __attribute__((address_space(1))) void*)(gA + (size_t)i * 32 * KT + kt),
                (__attribute__((address_space(3))) void*)&sA[(i * 32 + wid * 8) * 64],
                16, 0, 0);
            __builtin_amdgcn_global_load_lds(
                (const __attribute__((address_space(1))) void*)(gB + (size_t)i * 32 * KT + kt),
                (__attribute__((address_space(3))) void*)&sB[(i * 32 + wid * 8) * 64],
                16, 0, 0);
        }
        __syncthreads();
#pragma unroll
        for (int ks = 0; ks < 2; ++ks) {
            bf16x8 af[4], bfr[4];
#pragma unroll
            for (int mf = 0; mf < 4; ++mf)
                af[mf] = *(const bf16x8*)&sA[(wm * 64 + mf * 16 + (lane & 15)) * 64 + ks * 32 + (lane >> 4) * 8];
#pragma unroll
            for (int nf = 0; nf < 4; ++nf)
                bfr[nf] = *(const bf16x8*)&sB[(wn * 64 + nf * 16 + (lane & 15)) * 64 + ks * 32 + (lane >> 4) * 8];
#pragma unroll
            for (int mf = 0; mf < 4; ++mf)
#pragma unroll
                for (int nf = 0; nf < 4; ++nf)
                    acc[mf][nf] = __builtin_amdgcn_mfma_f32_16x16x32_bf16(
                        af[mf], bfr[nf], acc[mf][nf], 0, 0, 0);
        }
        __syncthreads();
    }

    float* Cs = C + (size_t)blockIdx.y * MT * NT;
    int row0 = m0 + wm * 64 + (lane >> 4) * 4;
    int col0 = n0 + wn * 64 + (lane & 15);
#pragma unroll
    for (int mf = 0; mf < 4; ++mf)
#pragma unroll
        for (int nf = 0; nf < 4; ++nf) {
            int rr = row0 + mf * 16;
            int cc = col0 + nf * 16;
#pragma unroll
            for (int v = 0; v < 4; ++v)
                Cs[(size_t)(rr + v) * NT + cc] = acc[mf][nf][v];
        }
}

// ---------------------------------------------------------------------------
// pass4b: out[b,d,p,r] = sum_s Ct[s][r*128 + d][b*1024 + p]
// ---------------------------------------------------------------------------
template <int SPLIT, typename CTYPE>
__global__ __launch_bounds__(256) void pass4b(const CTYPE* __restrict__ Ct,
                                              float* __restrict__ out) {
    __shared__ float lds[12 * 256];
    int bid = blockIdx.x;
    int pch = bid & 3;
    int d   = (bid >> 2) & 127;
    int b   = bid >> 9;
    int p0  = pch * 256;
    int t   = threadIdx.x;
#pragma unroll
    for (int r = 0; r < 12; ++r) {
        size_t off = (size_t)(r * D_ + d) * NT + b * P_ + p0 + t;
        float s = 0.f;
#pragma unroll
        for (int sp = 0; sp < SPLIT; ++sp) {
            CTYPE v = Ct[(size_t)sp * MT * NT + off];
            if constexpr (sizeof(CTYPE) == 2) s += bf2f(v);
            else                              s += v;
        }
        lds[r * 256 + t] = s;
    }
    __syncthreads();
    float* obase = out + ((size_t)((b * D_ + d) * P_ + p0)) * 12;
#pragma unroll
    for (int q = 0; q < 3; ++q) {
        int e0 = q * 1024 + t * 4;
        float4 v;
        { int e = e0 + 0; int p = e / 12; int r = e - p * 12; v.x = lds[r * 256 + p]; }
        { int e = e0 + 1; int p = e / 12; int r = e - p * 12; v.y = lds[r * 256 + p]; }
        { int e = e0 + 2; int p = e / 12; int r = e - p * 12; v.z = lds[r * 256 + p]; }
        { int e = e0 + 3; int p = e / 12; int r = e - p * 12; v.w = lds[r * 256 + p]; }
        *(float4*)(obase + e0) = v;
    }
}

// ---------------------------------------------------------------------------
// fallback: direct naive computation
// ---------------------------------------------------------------------------
__global__ __launch_bounds__(256) void naive_kernel(const float* __restrict__ x,
                                                    const float* __restrict__ W,
                                                    const int* __restrict__ kidx3,
                                                    const int* __restrict__ aidx3,
                                                    float* __restrict__ out) {
    long long t = (long long)blockIdx.x * 256 + threadIdx.x;
    if (t >= (long long)B_ * D_ * P_ * R_) return;
    int r = (int)(t % 12);
    int p = (int)((t / 12) % P_);
    int d = (int)((t / (12 * P_)) % D_);
    int b = (int)(t / (12 * (long long)P_ * D_));
    int kk[K_];
    int aa[A_];
#pragma unroll
    for (int k = 0; k < K_; ++k) kk[k] = kidx3[(k * 12 + 0) * 12 + r];
#pragma unroll
    for (int a = 0; a < A_; ++a) aa[a] = aidx3[(0 * 12 + a) * 12 + r];
    float sum = 0.f;
    for (int c = 0; c < C_; ++c) {
        const float* wrow = W + (size_t)(d * C_ + c) * 60;
        const float* xrow = x + ((size_t)(b * C_ + c) * K_) * (P_ * A_) + (size_t)p * A_;
        for (int k = 0; k < K_; ++k) {
            const float* wk = wrow + kk[k] * 12;
            const float* xk = xrow + (size_t)k * (P_ * A_);
#pragma unroll
            for (int a = 0; a < A_; ++a) sum += wk[aa[a]] * xk[a];
        }
    }
    out[t] = sum;
}

extern "C" void kernel_launch(void* const* d_in, const int* in_sizes, int n_in,
                              void* d_out, int out_size, void* d_ws, size_t ws_size,
                              hipStream_t stream) {
    const float* x     = (const float*)d_in[0];
    const float* W     = (const float*)d_in[1];
    const int*   kidx3 = (const int*)d_in[2];
    const int*   aidx3 = (const int*)d_in[3];
    float*       out   = (float*)d_out;

    const size_t XB  = (size_t)NT * KT * 2;   // 167,772,160
    const size_t WB  = (size_t)MT * KT * 2;   //  62,914,560
    const size_t CTf = (size_t)MT * NT * 4;   //  25,165,824 (f32 slab)
    const size_t CTh = (size_t)MT * NT * 2;   //  12,582,912 (bf16 slab)

    if (ws_size >= XB + WB + 8 * CTf) {
        u16*   Xb = (u16*)d_ws;
        u16*   Wb = (u16*)((char*)d_ws + XB);
        float* Ct = (float*)((char*)d_ws + XB + WB);
        pass1_xt<<<dim3(16, 128, 4), 256, 0, stream>>>(x, Xb);
        pass2_wb<<<(MT * (KT / 8)) / 256, 256, 0, stream>>>(W, kidx3, aidx3, Wb);
        gemm256<8, float><<<dim3(96, 8), 512, 0, stream>>>(Wb, Xb, Ct);
        pass4b<8, float><<<2048, 256, 0, stream>>>(Ct, out);
    } else if (ws_size >= XB + WB + 8 * CTh) {
        // bf16 partials (fits 332 MB): ~+0.03 absmax vs 0.259 threshold
        u16* Xb = (u16*)d_ws;
        u16* Wb = (u16*)((char*)d_ws + XB);
        u16* Ct = (u16*)((char*)d_ws + XB + WB);
        pass1_xt<<<dim3(16, 128, 4), 256, 0, stream>>>(x, Xb);
        pass2_wb<<<(MT * (KT / 8)) / 256, 256, 0, stream>>>(W, kidx3, aidx3, Wb);
        gemm256<8, u16><<<dim3(96, 8), 512, 0, stream>>>(Wb, Xb, Ct);
        pass4b<8, u16><<<2048, 256, 0, stream>>>(Ct, out);
    } else if (ws_size >= XB + WB + CTf) {
        u16*   Xb = (u16*)d_ws;
        u16*   Wb = (u16*)((char*)d_ws + XB);
        float* Ct = (float*)((char*)d_ws + XB + WB);
        pass1_xt<<<dim3(16, 128, 4), 256, 0, stream>>>(x, Xb);
        pass2_wb<<<(MT * (KT / 8)) / 256, 256, 0, stream>>>(W, kidx3, aidx3, Wb);
        gemm128<1><<<dim3(384, 1), 256, 0, stream>>>(Wb, Xb, Ct);
        pass4b<1, float><<<2048, 256, 0, stream>>>(Ct, out);
    } else {
        naive_kernel<<<(B_ * D_ * P_ * R_) / 256, 256, 0, stream>>>(x, W, kidx3, aidx3, out);
    }
}

// Round 4
// 552.723 us; speedup vs baseline: 1.3552x; 1.1171x over previous
//
#include <hip/hip_runtime.h>
#include <hip/hip_bf16.h>

typedef __bf16 bf16x8 __attribute__((ext_vector_type(8)));
typedef float f32x4 __attribute__((ext_vector_type(4)));
typedef unsigned short u16;
typedef unsigned int u32;

// Problem constants
#define B_   4
#define C_   128
#define K_   13
#define A_   12
#define P_   1024
#define D_   128
#define R_   12
// GEMM dims: M = R_*D_ = 1536, N = B_*P_ = 4096, K padded: 156 -> 160 per c
#define KT   20480   // 128 * 160
#define MT   1536
#define NT   4096

__device__ __forceinline__ u16 f2bf(float f) {
    u32 u = __builtin_bit_cast(u32, f);
    u32 r = (u + 0x7FFFu + ((u >> 16) & 1u)) >> 16;
    return (u16)r;
}
__device__ __forceinline__ float bf2f(u16 v) {
    u32 u = (u32)v << 16;
    return __builtin_bit_cast(float, u);
}

__device__ __forceinline__ void barrier_() {
    asm volatile("" ::: "memory");
    __builtin_amdgcn_s_barrier();
    asm volatile("" ::: "memory");
}
__device__ __forceinline__ void lgkm0_() {
    asm volatile("s_waitcnt lgkmcnt(0)" ::: "memory");
    __builtin_amdgcn_sched_barrier(0);
}
#define VMW(n) asm volatile("s_waitcnt vmcnt(" #n ")" ::: "memory")

// ---------------------------------------------------------------------------
// pass1: x[b,c,k,p,a] f32  ->  Xb[n = b*1024+p][k_lin = c*160 + k*12 + a] bf16
// 256-row tiles, all 256 threads active, 2 blocks/CU (80 KB LDS)
// ---------------------------------------------------------------------------
__global__ __launch_bounds__(256) void pass1_xt(const float* __restrict__ x,
                                                u16* __restrict__ Xb) {
    __shared__ u16 lds[256 * 160];
    const int c  = blockIdx.y;
    const int b  = blockIdx.z;
    const int p0 = blockIdx.x * 256;
    const int t  = threadIdx.x;

    lds[t * 160 + 156] = 0;
    lds[t * 160 + 157] = 0;
    lds[t * 160 + 158] = 0;
    lds[t * 160 + 159] = 0;

    const float* xbase = x + ((size_t)(b * C_ + c)) * (K_ * (size_t)P_ * A_) + (size_t)p0 * A_;
    for (int k = 0; k < K_; ++k) {
        const float4* src = (const float4*)(xbase + (size_t)k * (P_ * A_));
#pragma unroll
        for (int it = 0; it < 3; ++it) {
            float4 v = src[t + it * 256];
            int e = (t + it * 256) * 4;
            float fv[4] = {v.x, v.y, v.z, v.w};
#pragma unroll
            for (int j = 0; j < 4; ++j) {
                int ee = e + j;
                int pl = ee / 12;
                int a  = ee - pl * 12;
                lds[pl * 160 + k * 12 + a] = f2bf(fv[j]);
            }
        }
    }
    __syncthreads();
    const int n0 = b * P_ + p0;
#pragma unroll
    for (int it = 0; it < 20; ++it) {
        int pi  = t + it * 256;
        int row = pi / 20;
        int pc  = pi % 20;
        uint4 v = *(const uint4*)&lds[row * 160 + pc * 8];
        *(uint4*)((char*)Xb + ((size_t)(n0 + row) * KT + c * 160 + pc * 8) * 2) = v;
    }
}

// ---------------------------------------------------------------------------
// pass2: Wb[m = r*128+d][k_lin] = bf16( W[d, c, kidx3[k,a,r], aidx3[k,a,r]] )
// ---------------------------------------------------------------------------
__global__ __launch_bounds__(256) void pass2_wb(const float* __restrict__ W,
                                                const int* __restrict__ kidx3,
                                                const int* __restrict__ aidx3,
                                                u16* __restrict__ Wb) {
    int t = blockIdx.x * 256 + threadIdx.x;
    int k8 = t % (KT / 8);
    int m  = t / (KT / 8);
    int r  = m >> 7;
    int d  = m & 127;
    int kl0 = k8 * 8;
    int c   = kl0 / 160;
    int e0  = kl0 - c * 160;
    u16 vals[8];
#pragma unroll
    for (int j = 0; j < 8; ++j) {
        int e = e0 + j;
        u16 o = 0;
        if (e < 156) {
            int k = e / 12;
            int a = e - k * 12;
            int kk = kidx3[(k * 12 + a) * 12 + r];
            int aa = aidx3[(k * 12 + a) * 12 + r];
            o = f2bf(W[((d * C_ + c) * 5 + kk) * 12 + aa]);
        }
        vals[j] = o;
    }
    uint4 v;
    v.x = (u32)vals[0] | ((u32)vals[1] << 16);
    v.y = (u32)vals[2] | ((u32)vals[3] << 16);
    v.z = (u32)vals[4] | ((u32)vals[5] << 16);
    v.w = (u32)vals[6] | ((u32)vals[7] << 16);
    *(uint4*)((char*)Wb + ((size_t)m * KT + kl0) * 2) = v;
}

// ---------------------------------------------------------------------------
// gemm256: 256x256 tile, BK=64, 8 waves (2M x 4N), dbuf LDS, T2 swizzle,
// 3 phases/K-tile with quadrant-aligned halves and DERIVED per-phase vmcnt.
//   ph0: read A-half0,B-half0; stage A1(u+1); MFMA mf0-3 x nf0-1; vm(10)
//   ph1: read B-half1;         stage B0,A0(u+2); MFMA mf0-3 x nf2-3; vm(12)
//   ph2: read A-half1;         stage B1(u+2);   MFMA mf4-7 x nf0-3; vm(10)
// Fragment mapping: A-half0 rows [0,128) hold mf0-3 (wm*64+mf*16+lq);
// B-half0 rows [0,128) hold nf0-1 (wn*32+nf*16+lq). Each phase's LDS reads
// touch exactly one staged half -> per-half waits with 5-6 phases of slack.
// ---------------------------------------------------------------------------
template <int SPLIT, typename CTYPE>
__global__ __launch_bounds__(512, 2) void gemm256(const u16* __restrict__ A,
                                                  const u16* __restrict__ Bt,
                                                  CTYPE* __restrict__ C) {
    __shared__ u16 sA[2][256 * 64];
    __shared__ u16 sB[2][256 * 64];

    const int NTL = (KT / SPLIT) / 64;           // K-tiles per block (40)
    int bid = blockIdx.x;                        // 96 tiles, 96 % 8 == 0
    int swz = (bid & 7) * 12 + (bid >> 3);       // XCD-contiguous, bijective
    int m0 = (swz % 6) * 256;
    int n0 = (swz / 6) * 256;
    int ks0 = blockIdx.y * (KT / SPLIT);

    int tid  = threadIdx.x;
    int lane = tid & 63;
    int wid  = tid >> 6;
    int wm   = wid >> 2;                         // 0..1
    int wn   = wid & 3;                          // 0..3
    int lq   = lane & 15;

    // per-lane pre-swizzled global source (linear LDS dest, rule #21)
    int schunk = (lane & 7) ^ (lane >> 3);
    const u16* gA = A  + (size_t)(m0 + wid * 16 + (lane >> 3)) * KT + ks0 + schunk * 8;
    const u16* gB = Bt + (size_t)(n0 + wid * 16 + (lane >> 3)) * KT + ks0 + schunk * 8;

    auto stA = [&](int buf, int t_, int h) {
#pragma unroll
        for (int i = 0; i < 2; ++i)
            __builtin_amdgcn_global_load_lds(
                (const __attribute__((address_space(1))) void*)(gA + (size_t)(h * 128 + i * 8) * KT + (size_t)t_ * 64),
                (__attribute__((address_space(3))) void*)&sA[buf][(h * 128 + wid * 16 + i * 8) * 64],
                16, 0, 0);
    };
    auto stB = [&](int buf, int t_, int h) {
#pragma unroll
        for (int i = 0; i < 2; ++i)
            __builtin_amdgcn_global_load_lds(
                (const __attribute__((address_space(1))) void*)(gB + (size_t)(h * 128 + i * 8) * KT + (size_t)t_ * 64),
                (__attribute__((address_space(3))) void*)&sB[buf][(h * 128 + wid * 16 + i * 8) * 64],
                16, 0, 0);
    };
    auto ldA = [&](int buf, int row, int ks) -> bf16x8 {
        int chunk = ((ks << 2) + (lane >> 4)) ^ (row & 7);
        return *(const bf16x8*)&sA[buf][row * 64 + chunk * 8];
    };
    auto ldB = [&](int buf, int row, int ks) -> bf16x8 {
        int chunk = ((ks << 2) + (lane >> 4)) ^ (row & 7);
        return *(const bf16x8*)&sB[buf][row * 64 + chunk * 8];
    };

    f32x4 acc[8][4];
#pragma unroll
    for (int i = 0; i < 8; ++i)
#pragma unroll
        for (int j = 0; j < 4; ++j) acc[i][j] = (f32x4){0.f, 0.f, 0.f, 0.f};

    // prologue FIFO: B0(0) A0(0) B1(0) A1(0) B0(1) A0(1) B1(1) = 14 loads
    stB(0, 0, 0); stA(0, 0, 0); stB(0, 0, 1); stA(0, 0, 1);
    stB(1, 1, 0); stA(1, 1, 0); stB(1, 1, 1);
    VMW(10);                      // B0(0),A0(0) landed; 10 stay in flight
    barrier_();

    bf16x8 af[4][2], bfr[4][2];

    for (int u = 0; u < NTL; ++u) {
        int cur = u & 1;
        int nxt = cur ^ 1;

        // ---- phase 0: read A-half0 + B-half0; stage A1(u+1); MFMA Q(mf0-3,nf0-1)
#pragma unroll
        for (int nf = 0; nf < 2; ++nf)
#pragma unroll
            for (int ks = 0; ks < 2; ++ks)
                bfr[nf][ks] = ldB(cur, wn * 32 + nf * 16 + lq, ks);
#pragma unroll
        for (int mf = 0; mf < 4; ++mf)
#pragma unroll
            for (int ks = 0; ks < 2; ++ks)
                af[mf][ks] = ldA(cur, wm * 64 + mf * 16 + lq, ks);
        if (u + 1 < NTL) stA(nxt, u + 1, 1);
        barrier_();
        lgkm0_();
        __builtin_amdgcn_s_setprio(1);
#pragma unroll
        for (int mf = 0; mf < 4; ++mf)
#pragma unroll
            for (int nf = 0; nf < 2; ++nf)
#pragma unroll
                for (int ks = 0; ks < 2; ++ks)
                    acc[mf][nf] = __builtin_amdgcn_mfma_f32_16x16x32_bf16(
                        af[mf][ks], bfr[nf][ks], acc[mf][nf], 0, 0, 0);
        __builtin_amdgcn_s_setprio(0);
        if (u + 1 < NTL) { VMW(10); } else { VMW(2); }   // gate B1(u)
        barrier_();

        // ---- phase 1: read B-half1; stage B0(u+2),A0(u+2); MFMA Q(mf0-3,nf2-3)
#pragma unroll
        for (int nf = 2; nf < 4; ++nf)
#pragma unroll
            for (int ks = 0; ks < 2; ++ks)
                bfr[nf][ks] = ldB(cur, 128 + wn * 32 + (nf - 2) * 16 + lq, ks);
        if (u + 2 < NTL) { stB(cur, u + 2, 0); stA(cur, u + 2, 0); }
        barrier_();
        lgkm0_();
        __builtin_amdgcn_s_setprio(1);
#pragma unroll
        for (int mf = 0; mf < 4; ++mf)
#pragma unroll
            for (int nf = 2; nf < 4; ++nf)
#pragma unroll
                for (int ks = 0; ks < 2; ++ks)
                    acc[mf][nf] = __builtin_amdgcn_mfma_f32_16x16x32_bf16(
                        af[mf][ks], bfr[nf][ks], acc[mf][nf], 0, 0, 0);
        __builtin_amdgcn_s_setprio(0);
        if (u + 2 < NTL)      { VMW(12); }               // gate A1(u)
        else if (u + 1 < NTL) { VMW(8); }
        else                  { VMW(0); }
        barrier_();

        // ---- phase 2: read A-half1; stage B1(u+2); MFMA Q(mf4-7,nf0-3)
#pragma unroll
        for (int mf = 0; mf < 4; ++mf)
#pragma unroll
            for (int ks = 0; ks < 2; ++ks)
                af[mf][ks] = ldA(cur, 128 + wm * 64 + mf * 16 + lq, ks);
        if (u + 2 < NTL) stB(cur, u + 2, 1);
        barrier_();
        lgkm0_();
        __builtin_amdgcn_s_setprio(1);
#pragma unroll
        for (int mf = 0; mf < 4; ++mf)
#pragma unroll
            for (int nf = 0; nf < 4; ++nf)
#pragma unroll
                for (int ks = 0; ks < 2; ++ks)
                    acc[mf + 4][nf] = __builtin_amdgcn_mfma_f32_16x16x32_bf16(
                        af[mf][ks], bfr[nf][ks], acc[mf + 4][nf], 0, 0, 0);
        __builtin_amdgcn_s_setprio(0);
        if (u + 1 < NTL) {
            if (u + 2 < NTL) { VMW(10); } else { VMW(4); }  // gate B0,A0(u+1)
            barrier_();
        }
    }
    VMW(0);

    // epilogue: store partial tile (quadrant mapping) to slab blockIdx.y
    CTYPE* Cs = C + (size_t)blockIdx.y * ((size_t)MT * NT);
#pragma unroll
    for (int mf = 0; mf < 8; ++mf) {
        int rr = m0 + (mf >= 4 ? 128 : 0) + wm * 64 + (mf & 3) * 16 + ((lane >> 4) << 2);
#pragma unroll
        for (int nf = 0; nf < 4; ++nf) {
            int cc = n0 + (nf >= 2 ? 128 : 0) + wn * 32 + (nf & 1) * 16 + lq;
#pragma unroll
            for (int v = 0; v < 4; ++v) {
                size_t idx = (size_t)(rr + v) * NT + cc;
                if constexpr (sizeof(CTYPE) == 2) Cs[idx] = f2bf(acc[mf][nf][v]);
                else                              Cs[idx] = acc[mf][nf][v];
            }
        }
    }
}

// ---------------------------------------------------------------------------
// gemm128 (proven fallback): 128x128 tile, 2-barrier loop
// ---------------------------------------------------------------------------
template <int SPLIT>
__global__ __launch_bounds__(256) void gemm128(const u16* __restrict__ A,
                                               const u16* __restrict__ Bt,
                                               float* __restrict__ C) {
    __shared__ u16 sA[128 * 64];
    __shared__ u16 sB[128 * 64];

    int bid = blockIdx.x;
    int swz = (bid & 7) * 48 + (bid >> 3);
    int mt = swz % 12;
    int nt = swz / 12;
    int m0 = mt * 128;
    int n0 = nt * 128;
    int ks0 = blockIdx.y * (KT / SPLIT);

    int tid  = threadIdx.x;
    int lane = tid & 63;
    int wid  = tid >> 6;
    int wm   = wid >> 1;
    int wn   = wid & 1;

    int srow = wid * 8 + (lane >> 3);
    int spc  = lane & 7;
    const u16* gA = A  + (size_t)(m0 + srow) * KT + spc * 8;
    const u16* gB = Bt + (size_t)(n0 + srow) * KT + spc * 8;

    f32x4 acc[4][4];
#pragma unroll
    for (int i = 0; i < 4; ++i)
#pragma unroll
        for (int j = 0; j < 4; ++j) acc[i][j] = (f32x4){0.f, 0.f, 0.f, 0.f};

    for (int kt = ks0; kt < ks0 + KT / SPLIT; kt += 64) {
#pragma unroll
        for (int i = 0; i < 4; ++i) {
            __builtin_amdgcn_global_load_lds(
                (const __attribute__((address_space(1))) void*)(gA + (size_t)i * 32 * KT + kt),
                (__attribute__((address_space(3))) void*)&sA[(i * 32 + wid * 8) * 64],
                16, 0, 0);
            __builtin_amdgcn_global_load_lds(
                (const __attribute__((address_space(1))) void*)(gB + (size_t)i * 32 * KT + kt),
                (__attribute__((address_space(3))) void*)&sB[(i * 32 + wid * 8) * 64],
                16, 0, 0);
        }
        __syncthreads();
#pragma unroll
        for (int ks = 0; ks < 2; ++ks) {
            bf16x8 af[4], bfr[4];
#pragma unroll
            for (int mf = 0; mf < 4; ++mf)
                af[mf] = *(const bf16x8*)&sA[(wm * 64 + mf * 16 + (lane & 15)) * 64 + ks * 32 + (lane >> 4) * 8];
#pragma unroll
            for (int nf = 0; nf < 4; ++nf)
                bfr[nf] = *(const bf16x8*)&sB[(wn * 64 + nf * 16 + (lane & 15)) * 64 + ks * 32 + (lane >> 4) * 8];
#pragma unroll
            for (int mf = 0; mf < 4; ++mf)
#pragma unroll
                for (int nf = 0; nf < 4; ++nf)
                    acc[mf][nf] = __builtin_amdgcn_mfma_f32_16x16x32_bf16(
                        af[mf], bfr[nf], acc[mf][nf], 0, 0, 0);
        }
        __syncthreads();
    }

    float* Cs = C + (size_t)blockIdx.y * MT * NT;
    int row0 = m0 + wm * 64 + (lane >> 4) * 4;
    int col0 = n0 + wn * 64 + (lane & 15);
#pragma unroll
    for (int mf = 0; mf < 4; ++mf)
#pragma unroll
        for (int nf = 0; nf < 4; ++nf) {
            int rr = row0 + mf * 16;
            int cc = col0 + nf * 16;
#pragma unroll
            for (int v = 0; v < 4; ++v)
                Cs[(size_t)(rr + v) * NT + cc] = acc[mf][nf][v];
        }
}

// ---------------------------------------------------------------------------
// pass4b: out[b,d,p,r] = sum_s Ct[s][r*128 + d][b*1024 + p]
// ---------------------------------------------------------------------------
template <int SPLIT, typename CTYPE>
__global__ __launch_bounds__(256) void pass4b(const CTYPE* __restrict__ Ct,
                                              float* __restrict__ out) {
    __shared__ float lds[12 * 256];
    int bid = blockIdx.x;
    int pch = bid & 3;
    int d   = (bid >> 2) & 127;
    int b   = bid >> 9;
    int p0  = pch * 256;
    int t   = threadIdx.x;
#pragma unroll
    for (int r = 0; r < 12; ++r) {
        size_t off = (size_t)(r * D_ + d) * NT + b * P_ + p0 + t;
        float s = 0.f;
#pragma unroll
        for (int sp = 0; sp < SPLIT; ++sp) {
            CTYPE v = Ct[(size_t)sp * MT * NT + off];
            if constexpr (sizeof(CTYPE) == 2) s += bf2f(v);
            else                              s += v;
        }
        lds[r * 256 + t] = s;
    }
    __syncthreads();
    float* obase = out + ((size_t)((b * D_ + d) * P_ + p0)) * 12;
#pragma unroll
    for (int q = 0; q < 3; ++q) {
        int e0 = q * 1024 + t * 4;
        float4 v;
        { int e = e0 + 0; int p = e / 12; int r = e - p * 12; v.x = lds[r * 256 + p]; }
        { int e = e0 + 1; int p = e / 12; int r = e - p * 12; v.y = lds[r * 256 + p]; }
        { int e = e0 + 2; int p = e / 12; int r = e - p * 12; v.z = lds[r * 256 + p]; }
        { int e = e0 + 3; int p = e / 12; int r = e - p * 12; v.w = lds[r * 256 + p]; }
        *(float4*)(obase + e0) = v;
    }
}

// ---------------------------------------------------------------------------
// fallback: direct naive computation
// ---------------------------------------------------------------------------
__global__ __launch_bounds__(256) void naive_kernel(const float* __restrict__ x,
                                                    const float* __restrict__ W,
                                                    const int* __restrict__ kidx3,
                                                    const int* __restrict__ aidx3,
                                                    float* __restrict__ out) {
    long long t = (long long)blockIdx.x * 256 + threadIdx.x;
    if (t >= (long long)B_ * D_ * P_ * R_) return;
    int r = (int)(t % 12);
    int p = (int)((t / 12) % P_);
    int d = (int)((t / (12 * P_)) % D_);
    int b = (int)(t / (12 * (long long)P_ * D_));
    int kk[K_];
    int aa[A_];
#pragma unroll
    for (int k = 0; k < K_; ++k) kk[k] = kidx3[(k * 12 + 0) * 12 + r];
#pragma unroll
    for (int a = 0; a < A_; ++a) aa[a] = aidx3[(0 * 12 + a) * 12 + r];
    float sum = 0.f;
    for (int c = 0; c < C_; ++c) {
        const float* wrow = W + (size_t)(d * C_ + c) * 60;
        const float* xrow = x + ((size_t)(b * C_ + c) * K_) * (P_ * A_) + (size_t)p * A_;
        for (int k = 0; k < K_; ++k) {
            const float* wk = wrow + kk[k] * 12;
            const float* xk = xrow + (size_t)k * (P_ * A_);
#pragma unroll
            for (int a = 0; a < A_; ++a) sum += wk[aa[a]] * xk[a];
        }
    }
    out[t] = sum;
}

extern "C" void kernel_launch(void* const* d_in, const int* in_sizes, int n_in,
                              void* d_out, int out_size, void* d_ws, size_t ws_size,
                              hipStream_t stream) {
    const float* x     = (const float*)d_in[0];
    const float* W     = (const float*)d_in[1];
    const int*   kidx3 = (const int*)d_in[2];
    const int*   aidx3 = (const int*)d_in[3];
    float*       out   = (float*)d_out;

    const size_t XB  = (size_t)NT * KT * 2;   // 167,772,160
    const size_t WB  = (size_t)MT * KT * 2;   //  62,914,560
    const size_t CTf = (size_t)MT * NT * 4;   //  25,165,824 (f32 slab)
    const size_t CTh = (size_t)MT * NT * 2;   //  12,582,912 (bf16 slab)

    if (ws_size >= XB + WB + 8 * CTh) {
        // split-K x8, bf16 partial slabs (halves gemm-write + pass4-read traffic)
        u16* Xb = (u16*)d_ws;
        u16* Wb = (u16*)((char*)d_ws + XB);
        u16* Ct = (u16*)((char*)d_ws + XB + WB);
        pass1_xt<<<dim3(4, 128, 4), 256, 0, stream>>>(x, Xb);
        pass2_wb<<<(MT * (KT / 8)) / 256, 256, 0, stream>>>(W, kidx3, aidx3, Wb);
        gemm256<8, u16><<<dim3(96, 8), 512, 0, stream>>>(Wb, Xb, Ct);
        pass4b<8, u16><<<2048, 256, 0, stream>>>(Ct, out);
    } else if (ws_size >= XB + WB + CTf) {
        u16*   Xb = (u16*)d_ws;
        u16*   Wb = (u16*)((char*)d_ws + XB);
        float* Ct = (float*)((char*)d_ws + XB + WB);
        pass1_xt<<<dim3(4, 128, 4), 256, 0, stream>>>(x, Xb);
        pass2_wb<<<(MT * (KT / 8)) / 256, 256, 0, stream>>>(W, kidx3, aidx3, Wb);
        gemm128<1><<<dim3(384, 1), 256, 0, stream>>>(Wb, Xb, Ct);
        pass4b<1, float><<<2048, 256, 0, stream>>>(Ct, out);
    } else {
        naive_kernel<<<(B_ * D_ * P_ * R_) / 256, 256, 0, stream>>>(x, W, kidx3, aidx3, out);
    }
}

// Round 6
// 363.749 us; speedup vs baseline: 2.0592x; 1.5195x over previous
//
#include <hip/hip_runtime.h>
#include <hip/hip_bf16.h>

typedef __bf16 bf16x8 __attribute__((ext_vector_type(8)));
typedef __bf16 bf16x4 __attribute__((ext_vector_type(4)));
typedef float f32x4 __attribute__((ext_vector_type(4)));
typedef float f32x3 __attribute__((ext_vector_type(3)));
typedef unsigned int u32x3 __attribute__((ext_vector_type(3)));
typedef unsigned short u16;
typedef unsigned int u32;

// Problem constants
#define B_   4
#define C_   128
#define K_   13
#define A_   12
#define P_   1024
#define D_   128
#define R_   12
// Old-path GEMM dims (fallback): K padded 156 -> 160 per c
#define KT   20480
#define MT   1536
#define NT   4096
// New-path dims: K' = 5 groups * 128c * 12a = 7680 = 80 tiles of 96
#define KP   7680

#define AS1 __attribute__((address_space(1)))
#define AS3 __attribute__((address_space(3)))

__device__ __forceinline__ u16 f2bf(float f) {
    u32 u = __builtin_bit_cast(u32, f);
    u32 r = (u + 0x7FFFu + ((u >> 16) & 1u)) >> 16;
    return (u16)r;
}
__device__ __forceinline__ float bf2f(u16 v) {
    u32 u = (u32)v << 16;
    return __builtin_bit_cast(float, u);
}
__device__ __forceinline__ u32 pack2(float lo, float hi) {
    return (u32)f2bf(lo) | ((u32)f2bf(hi) << 16);
}

__device__ __forceinline__ void barrier_() {
    asm volatile("" ::: "memory");
    __builtin_amdgcn_s_barrier();
    asm volatile("" ::: "memory");
}
__device__ __forceinline__ void lgkm0_() {
    asm volatile("s_waitcnt lgkmcnt(0)" ::: "memory");
    __builtin_amdgcn_sched_barrier(0);
}
#define VMW(n) asm volatile("s_waitcnt vmcnt(" #n ")" ::: "memory")

// ===========================================================================
// NEW PATH
// ===========================================================================

// ---------------------------------------------------------------------------
// poolk: x[b,c,k,p,a] f32 -> pool[j][c][n=b*1024+p][a] bf16, j in [0,26):
//   j=0..12 : raw k-slices;  j=13 : T = sum_{k<12} x;  j=14+r : N_r = shell1 sum
// ---------------------------------------------------------------------------
__global__ __launch_bounds__(512) void poolk(const float* __restrict__ x,
                                             const int* __restrict__ kidx3,
                                             u16* __restrict__ pool) {
    const int c = blockIdx.x;
    const int b = blockIdx.y;
    const int t = threadIdx.x;
    const int ah = t & 1, aoff = ah * 6;

    u32 m1[12];
#pragma unroll
    for (int k = 0; k < 12; ++k) {
        u32 m = 0;
#pragma unroll
        for (int r = 0; r < 12; ++r)
            m |= (kidx3[k * 144 + r] == 1 ? 1u : 0u) << r;
        m1[k] = m;
    }

    const float* xb = x + (size_t)(b * C_ + c) * (K_ * (size_t)P_ * A_);
    const size_t cslab = ((size_t)c * 4096) * 12;
    const size_t jstride = (size_t)C_ * 4096 * 12;

    for (int pp = 0; pp < 4; ++pp) {
        int p = pp * 256 + (t >> 1);
        int n = b * P_ + p;
        size_t obase = cslab + (size_t)n * 12 + aoff;
        float T[6] = {0.f, 0.f, 0.f, 0.f, 0.f, 0.f};
        float N[12][6];
#pragma unroll
        for (int r = 0; r < 12; ++r)
#pragma unroll
            for (int j = 0; j < 6; ++j) N[r][j] = 0.f;

#pragma unroll
        for (int k = 0; k < 13; ++k) {
            const float* s = xb + (size_t)k * (P_ * A_) + p * 12 + aoff;
            f32x3 v0 = *(const f32x3*)s;
            f32x3 v1 = *(const f32x3*)(s + 3);
            float v[6] = {v0.x, v0.y, v0.z, v1.x, v1.y, v1.z};
            u32x3 o;
            o.x = pack2(v[0], v[1]); o.y = pack2(v[2], v[3]); o.z = pack2(v[4], v[5]);
            *(u32x3*)(pool + (size_t)k * jstride + obase) = o;
            if (k < 12) {
#pragma unroll
                for (int j = 0; j < 6; ++j) T[j] += v[j];
                u32 m = m1[k];
#pragma unroll
                for (int r = 0; r < 12; ++r) {
                    if (m & (1u << r)) {
#pragma unroll
                        for (int j = 0; j < 6; ++j) N[r][j] += v[j];
                    }
                }
            }
        }
        {
            u32x3 o;
            o.x = pack2(T[0], T[1]); o.y = pack2(T[2], T[3]); o.z = pack2(T[4], T[5]);
            *(u32x3*)(pool + (size_t)13 * jstride + obase) = o;
        }
#pragma unroll
        for (int r = 0; r < 12; ++r) {
            u32x3 o;
            o.x = pack2(N[r][0], N[r][1]); o.y = pack2(N[r][2], N[r][3]); o.z = pack2(N[r][4], N[r][5]);
            *(u32x3*)(pool + (size_t)(14 + r) * jstride + obase) = o;
        }
    }
}

// ---------------------------------------------------------------------------
// abuild: tile-major panels Ab[r][tile][d][96] bf16 (each (r,tile) panel is a
// contiguous 24576-B byte-image of the LDS A-tile, XOR swizzle baked in:
// phys chunk chp holds logical chunk chp ^ ((d>>1)&3) within each ks-group).
// Values: g0:(W0-W2) g1:(W1-W2) g2:W2 g3:(W3-W2) g4:W4 at aa = aidx[a,r],
// logical col q = g*1536 + c*12 + a.
// ---------------------------------------------------------------------------
__global__ __launch_bounds__(256) void abuild(const float* __restrict__ W,
                                              const int* __restrict__ aidx3,
                                              u16* __restrict__ Ab) {
    int gidx = blockIdx.x * 256 + threadIdx.x;   // 12*128*960 = 1,474,560
    int r   = gidx / (128 * 960);
    int rem = gidx - r * (128 * 960);
    int d   = rem / 960;
    int p8  = rem - d * 960;
    int phys = p8 * 8;
    int tile = phys / 96;
    int w96  = phys - tile * 96;
    int ks   = w96 >> 5;
    int chp  = (w96 >> 3) & 3;
    int ch   = chp ^ ((d >> 1) & 3);
    int qbase = tile * 96 + ks * 32 + ch * 8;
    u16 o[8];
#pragma unroll
    for (int e = 0; e < 8; ++e) {
        int q  = qbase + e;
        int g  = q / 1536;
        int qq = q - g * 1536;
        int c  = qq / 12;
        int a  = qq - c * 12;
        int aa = aidx3[a * 12 + r];
        const float* wb = W + ((size_t)(d * C_ + c) * 5) * 12 + aa;
        float val;
        if (g == 2)      val = wb[2 * 12];
        else if (g == 4) val = wb[4 * 12];
        else             val = wb[g * 12] - wb[2 * 12];
        o[e] = f2bf(val);
    }
    uint4 v;
    v.x = (u32)o[0] | ((u32)o[1] << 16);
    v.y = (u32)o[2] | ((u32)o[3] << 16);
    v.z = (u32)o[4] | ((u32)o[5] << 16);
    v.w = (u32)o[6] | ((u32)o[7] << 16);
    *(uint4*)(Ab + (((size_t)(r * 80 + tile) * 128 + d) * 96 + w96)) = v;
}

// ---------------------------------------------------------------------------
// gemmS: per r: C_r[d][n] = sum_{q<7680} Ab_r[d][q] * B_r[n][q]
// BM=128 (all d), BN=256, BK=96, 8 waves (2Mx4N), dbuf LDS.
// Staging: 16-BYTE global_load_lds ONLY (flat byte copies):
//   A: contiguous (r,tile) panel -> 3 x 1KB per wave
//   B: contiguous (c, n-block) pool slab (256n x 24B) -> 6 x 1KB per wave
// 9 issues/wave/tile -> counted vmcnt(9), vmcnt(0) only at the tail.
// Split-K x4 -> bf16 partial slabs (pass4b reduces).
// ---------------------------------------------------------------------------
__global__ __launch_bounds__(512) void gemmS(const u16* __restrict__ Ab,
                                             const u16* __restrict__ pool,
                                             const int* __restrict__ kidx3,
                                             u16* __restrict__ C) {
    __shared__ __align__(16) u16 sA[2][128 * 96];
    __shared__ __align__(16) u16 sB[2][8 * 256 * 12];

    int bx = blockIdx.x;                 // 768 = 16nt * 12r * 4sp
    int nt = bx & 15;
    int r  = (bx >> 4) % 12;
    int sp = bx / 192;
    int n0 = nt * 256;

    int k0r = 0, k3r = 0;
    for (int k = 0; k < 13; ++k) {
        int kv = kidx3[k * 144 + r];
        if (kv == 0) k0r = k;
        if (kv == 3) k3r = k;
    }

    int lane = threadIdx.x & 63;
    int w    = threadIdx.x >> 6;
    int wm   = w >> 2, wn = w & 3;
    int lq   = lane & 15;

    auto stageA = [&](int buf, int tile) {
        const char* src = (const char*)(Ab + (size_t)(r * 80 + tile) * (128 * 96))
                        + w * 3072 + lane * 16;
#pragma unroll
        for (int i = 0; i < 3; ++i)
            __builtin_amdgcn_global_load_lds(
                (const AS1 void*)(src + i * 1024),
                (AS3 void*)&sA[buf][w * 1536 + i * 512],
                16, 0, 0);
    };
    auto stageB = [&](int buf, int tile) {
        int gt = tile >> 4;
        int c  = ((tile & 15) << 3) + w;
        int j  = (gt == 0) ? k0r : (gt == 1) ? (14 + r) : (gt == 2) ? 13
               : (gt == 3) ? k3r : 12;
        const char* src = (const char*)(pool + ((size_t)(j * C_ + c) * 4096 + n0) * 12)
                        + lane * 16;
#pragma unroll
        for (int i = 0; i < 6; ++i)
            __builtin_amdgcn_global_load_lds(
                (const AS1 void*)(src + i * 1024),
                (AS3 void*)&sB[buf][w * 3072 + i * 512],
                16, 0, 0);
    };
    auto ldA = [&](int buf, int m, int ks) -> bf16x8 {
        int ch = (lane >> 4) ^ ((m >> 1) & 3);
        return *(const bf16x8*)&sA[buf][m * 96 + ks * 32 + ch * 8];
    };
    auto ldB = [&](int buf, int n, int ks) -> bf16x8 {
        int q0 = ks * 32 + (lane >> 4) * 8;
        int c1 = q0 / 12, a1 = q0 - c1 * 12;
        int q2 = q0 + 4;
        int c2 = q2 / 12, a2 = q2 - c2 * 12;
        bf16x4 lo = *(const bf16x4*)&sB[buf][c1 * 3072 + n * 12 + a1];
        bf16x4 hi = *(const bf16x4*)&sB[buf][c2 * 3072 + n * 12 + a2];
        return __builtin_shufflevector(lo, hi, 0, 1, 2, 3, 4, 5, 6, 7);
    };

    f32x4 acc[4][4];
#pragma unroll
    for (int i = 0; i < 4; ++i)
#pragma unroll
        for (int j = 0; j < 4; ++j) acc[i][j] = (f32x4){0.f, 0.f, 0.f, 0.f};

    const int NTL2 = 20;               // 80 K-tiles / 4 splits
    int t0 = sp * NTL2;

    stageA(0, t0);
    stageB(0, t0);

    for (int u = 0; u < NTL2; ++u) {
        int cur = u & 1;
        if (u + 1 < NTL2) {
            stageA(cur ^ 1, t0 + u + 1);
            stageB(cur ^ 1, t0 + u + 1);
            VMW(9);
        } else {
            VMW(0);
        }
        barrier_();
#pragma unroll
        for (int ks = 0; ks < 3; ++ks) {
            bf16x8 af[4], bf_[4];
#pragma unroll
            for (int mf = 0; mf < 4; ++mf)
                af[mf] = ldA(cur, wm * 64 + mf * 16 + lq, ks);
#pragma unroll
            for (int nf = 0; nf < 4; ++nf)
                bf_[nf] = ldB(cur, wn * 64 + nf * 16 + lq, ks);
            lgkm0_();
            __builtin_amdgcn_s_setprio(1);
#pragma unroll
            for (int mf = 0; mf < 4; ++mf)
#pragma unroll
                for (int nf = 0; nf < 4; ++nf)
                    acc[mf][nf] = __builtin_amdgcn_mfma_f32_16x16x32_bf16(
                        af[mf], bf_[nf], acc[mf][nf], 0, 0, 0);
            __builtin_amdgcn_s_setprio(0);
        }
        barrier_();
    }

    u16* Cs = C + (size_t)sp * ((size_t)MT * NT);
#pragma unroll
    for (int mf = 0; mf < 4; ++mf)
#pragma unroll
        for (int nf = 0; nf < 4; ++nf) {
            int col = n0 + wn * 64 + nf * 16 + lq;
#pragma unroll
            for (int v = 0; v < 4; ++v) {
                int drow = wm * 64 + mf * 16 + ((lane >> 4) << 2) + v;
                Cs[(size_t)(r * 128 + drow) * NT + col] = f2bf(acc[mf][nf][v]);
            }
        }
}

// ===========================================================================
// OLD PATH (R4, proven) — fallback if workspace too small for the pool
// ===========================================================================

__global__ __launch_bounds__(256) void pass1_xt(const float* __restrict__ x,
                                                u16* __restrict__ Xb) {
    __shared__ u16 lds[256 * 160];
    const int c  = blockIdx.y;
    const int b  = blockIdx.z;
    const int p0 = blockIdx.x * 256;
    const int t  = threadIdx.x;

    lds[t * 160 + 156] = 0;
    lds[t * 160 + 157] = 0;
    lds[t * 160 + 158] = 0;
    lds[t * 160 + 159] = 0;

    const float* xbase = x + ((size_t)(b * C_ + c)) * (K_ * (size_t)P_ * A_) + (size_t)p0 * A_;
    for (int k = 0; k < K_; ++k) {
        const float4* src = (const float4*)(xbase + (size_t)k * (P_ * A_));
#pragma unroll
        for (int it = 0; it < 3; ++it) {
            float4 v = src[t + it * 256];
            int e = (t + it * 256) * 4;
            float fv[4] = {v.x, v.y, v.z, v.w};
#pragma unroll
            for (int j = 0; j < 4; ++j) {
                int ee = e + j;
                int pl = ee / 12;
                int a  = ee - pl * 12;
                lds[pl * 160 + k * 12 + a] = f2bf(fv[j]);
            }
        }
    }
    __syncthreads();
    const int n0 = b * P_ + p0;
#pragma unroll
    for (int it = 0; it < 20; ++it) {
        int pi  = t + it * 256;
        int row = pi / 20;
        int pc  = pi % 20;
        uint4 v = *(const uint4*)&lds[row * 160 + pc * 8];
        *(uint4*)((char*)Xb + ((size_t)(n0 + row) * KT + c * 160 + pc * 8) * 2) = v;
    }
}

__global__ __launch_bounds__(256) void pass2_wb(const float* __restrict__ W,
                                                const int* __restrict__ kidx3,
                                                const int* __restrict__ aidx3,
                                                u16* __restrict__ Wb) {
    int t = blockIdx.x * 256 + threadIdx.x;
    int k8 = t % (KT / 8);
    int m  = t / (KT / 8);
    int r  = m >> 7;
    int d  = m & 127;
    int kl0 = k8 * 8;
    int c   = kl0 / 160;
    int e0  = kl0 - c * 160;
    u16 vals[8];
#pragma unroll
    for (int j = 0; j < 8; ++j) {
        int e = e0 + j;
        u16 o = 0;
        if (e < 156) {
            int k = e / 12;
            int a = e - k * 12;
            int kk = kidx3[(k * 12 + a) * 12 + r];
            int aa = aidx3[(k * 12 + a) * 12 + r];
            o = f2bf(W[((d * C_ + c) * 5 + kk) * 12 + aa]);
        }
        vals[j] = o;
    }
    uint4 v;
    v.x = (u32)vals[0] | ((u32)vals[1] << 16);
    v.y = (u32)vals[2] | ((u32)vals[3] << 16);
    v.z = (u32)vals[4] | ((u32)vals[5] << 16);
    v.w = (u32)vals[6] | ((u32)vals[7] << 16);
    *(uint4*)((char*)Wb + ((size_t)m * KT + kl0) * 2) = v;
}

template <int SPLIT, typename CTYPE>
__global__ __launch_bounds__(512, 2) void gemm256(const u16* __restrict__ A,
                                                  const u16* __restrict__ Bt,
                                                  CTYPE* __restrict__ C) {
    __shared__ u16 sA[2][256 * 64];
    __shared__ u16 sB[2][256 * 64];

    const int NTL = (KT / SPLIT) / 64;
    int bid = blockIdx.x;
    int swz = (bid & 7) * 12 + (bid >> 3);
    int m0 = (swz % 6) * 256;
    int n0 = (swz / 6) * 256;
    int ks0 = blockIdx.y * (KT / SPLIT);

    int tid  = threadIdx.x;
    int lane = tid & 63;
    int wid  = tid >> 6;
    int wm   = wid >> 2;
    int wn   = wid & 3;
    int lq   = lane & 15;

    int schunk = (lane & 7) ^ (lane >> 3);
    const u16* gA = A  + (size_t)(m0 + wid * 16 + (lane >> 3)) * KT + ks0 + schunk * 8;
    const u16* gB = Bt + (size_t)(n0 + wid * 16 + (lane >> 3)) * KT + ks0 + schunk * 8;

    auto stA = [&](int buf, int t_, int h) {
#pragma unroll
        for (int i = 0; i < 2; ++i)
            __builtin_amdgcn_global_load_lds(
                (const AS1 void*)(gA + (size_t)(h * 128 + i * 8) * KT + (size_t)t_ * 64),
                (AS3 void*)&sA[buf][(h * 128 + wid * 16 + i * 8) * 64],
                16, 0, 0);
    };
    auto stB = [&](int buf, int t_, int h) {
#pragma unroll
        for (int i = 0; i < 2; ++i)
            __builtin_amdgcn_global_load_lds(
                (const AS1 void*)(gB + (size_t)(h * 128 + i * 8) * KT + (size_t)t_ * 64),
                (AS3 void*)&sB[buf][(h * 128 + wid * 16 + i * 8) * 64],
                16, 0, 0);
    };
    auto ldA = [&](int buf, int row, int ks) -> bf16x8 {
        int chunk = ((ks << 2) + (lane >> 4)) ^ (row & 7);
        return *(const bf16x8*)&sA[buf][row * 64 + chunk * 8];
    };
    auto ldB = [&](int buf, int row, int ks) -> bf16x8 {
        int chunk = ((ks << 2) + (lane >> 4)) ^ (row & 7);
        return *(const bf16x8*)&sB[buf][row * 64 + chunk * 8];
    };

    f32x4 acc[8][4];
#pragma unroll
    for (int i = 0; i < 8; ++i)
#pragma unroll
        for (int j = 0; j < 4; ++j) acc[i][j] = (f32x4){0.f, 0.f, 0.f, 0.f};

    stB(0, 0, 0); stA(0, 0, 0); stB(0, 0, 1); stA(0, 0, 1);
    stB(1, 1, 0); stA(1, 1, 0); stB(1, 1, 1);
    VMW(10);
    barrier_();

    bf16x8 af[4][2], bfr[4][2];

    for (int u = 0; u < NTL; ++u) {
        int cur = u & 1;
        int nxt = cur ^ 1;

#pragma unroll
        for (int nf = 0; nf < 2; ++nf)
#pragma unroll
            for (int ks = 0; ks < 2; ++ks)
                bfr[nf][ks] = ldB(cur, wn * 32 + nf * 16 + lq, ks);
#pragma unroll
        for (int mf = 0; mf < 4; ++mf)
#pragma unroll
            for (int ks = 0; ks < 2; ++ks)
                af[mf][ks] = ldA(cur, wm * 64 + mf * 16 + lq, ks);
        if (u + 1 < NTL) stA(nxt, u + 1, 1);
        barrier_();
        lgkm0_();
        __builtin_amdgcn_s_setprio(1);
#pragma unroll
        for (int mf = 0; mf < 4; ++mf)
#pragma unroll
            for (int nf = 0; nf < 2; ++nf)
#pragma unroll
                for (int ks = 0; ks < 2; ++ks)
                    acc[mf][nf] = __builtin_amdgcn_mfma_f32_16x16x32_bf16(
                        af[mf][ks], bfr[nf][ks], acc[mf][nf], 0, 0, 0);
        __builtin_amdgcn_s_setprio(0);
        if (u + 1 < NTL) { VMW(10); } else { VMW(2); }
        barrier_();

#pragma unroll
        for (int nf = 2; nf < 4; ++nf)
#pragma unroll
            for (int ks = 0; ks < 2; ++ks)
                bfr[nf][ks] = ldB(cur, 128 + wn * 32 + (nf - 2) * 16 + lq, ks);
        if (u + 2 < NTL) { stB(cur, u + 2, 0); stA(cur, u + 2, 0); }
        barrier_();
        lgkm0_();
        __builtin_amdgcn_s_setprio(1);
#pragma unroll
        for (int mf = 0; mf < 4; ++mf)
#pragma unroll
            for (int nf = 2; nf < 4; ++nf)
#pragma unroll
                for (int ks = 0; ks < 2; ++ks)
                    acc[mf][nf] = __builtin_amdgcn_mfma_f32_16x16x32_bf16(
                        af[mf][ks], bfr[nf][ks], acc[mf][nf], 0, 0, 0);
        __builtin_amdgcn_s_setprio(0);
        if (u + 2 < NTL)      { VMW(12); }
        else if (u + 1 < NTL) { VMW(8); }
        else                  { VMW(0); }
        barrier_();

#pragma unroll
        for (int mf = 0; mf < 4; ++mf)
#pragma unroll
            for (int ks = 0; ks < 2; ++ks)
                af[mf][ks] = ldA(cur, 128 + wm * 64 + mf * 16 + lq, ks);
        if (u + 2 < NTL) stB(cur, u + 2, 1);
        barrier_();
        lgkm0_();
        __builtin_amdgcn_s_setprio(1);
#pragma unroll
        for (int mf = 0; mf < 4; ++mf)
#pragma unroll
            for (int nf = 0; nf < 4; ++nf)
#pragma unroll
                for (int ks = 0; ks < 2; ++ks)
                    acc[mf + 4][nf] = __builtin_amdgcn_mfma_f32_16x16x32_bf16(
                        af[mf][ks], bfr[nf][ks], acc[mf + 4][nf], 0, 0, 0);
        __builtin_amdgcn_s_setprio(0);
        if (u + 1 < NTL) {
            if (u + 2 < NTL) { VMW(10); } else { VMW(4); }
            barrier_();
        }
    }
    VMW(0);

    CTYPE* Cs = C + (size_t)blockIdx.y * ((size_t)MT * NT);
#pragma unroll
    for (int mf = 0; mf < 8; ++mf) {
        int rr = m0 + (mf >= 4 ? 128 : 0) + wm * 64 + (mf & 3) * 16 + ((lane >> 4) << 2);
#pragma unroll
        for (int nf = 0; nf < 4; ++nf) {
            int cc = n0 + (nf >= 2 ? 128 : 0) + wn * 32 + (nf & 1) * 16 + lq;
#pragma unroll
            for (int v = 0; v < 4; ++v) {
                size_t idx = (size_t)(rr + v) * NT + cc;
                if constexpr (sizeof(CTYPE) == 2) Cs[idx] = f2bf(acc[mf][nf][v]);
                else                              Cs[idx] = acc[mf][nf][v];
            }
        }
    }
}

// ---------------------------------------------------------------------------
// pass4b: out[b,d,p,r] = sum_s Ct[s][r*128 + d][b*1024 + p]
// ---------------------------------------------------------------------------
template <int SPLIT, typename CTYPE>
__global__ __launch_bounds__(256) void pass4b(const CTYPE* __restrict__ Ct,
                                              float* __restrict__ out) {
    __shared__ float lds[12 * 256];
    int bid = blockIdx.x;
    int pch = bid & 3;
    int d   = (bid >> 2) & 127;
    int b   = bid >> 9;
    int p0  = pch * 256;
    int t   = threadIdx.x;
#pragma unroll
    for (int r = 0; r < 12; ++r) {
        size_t off = (size_t)(r * D_ + d) * NT + b * P_ + p0 + t;
        float s = 0.f;
#pragma unroll
        for (int sp = 0; sp < SPLIT; ++sp) {
            CTYPE v = Ct[(size_t)sp * MT * NT + off];
            if constexpr (sizeof(CTYPE) == 2) s += bf2f(v);
            else                              s += v;
        }
        lds[r * 256 + t] = s;
    }
    __syncthreads();
    float* obase = out + ((size_t)((b * D_ + d) * P_ + p0)) * 12;
#pragma unroll
    for (int q = 0; q < 3; ++q) {
        int e0 = q * 1024 + t * 4;
        float4 v;
        { int e = e0 + 0; int p = e / 12; int r = e - p * 12; v.x = lds[r * 256 + p]; }
        { int e = e0 + 1; int p = e / 12; int r = e - p * 12; v.y = lds[r * 256 + p]; }
        { int e = e0 + 2; int p = e / 12; int r = e - p * 12; v.z = lds[r * 256 + p]; }
        { int e = e0 + 3; int p = e / 12; int r = e - p * 12; v.w = lds[r * 256 + p]; }
        *(float4*)(obase + e0) = v;
    }
}

// ---------------------------------------------------------------------------
// fallback: direct naive computation
// ---------------------------------------------------------------------------
__global__ __launch_bounds__(256) void naive_kernel(const float* __restrict__ x,
                                                    const float* __restrict__ W,
                                                    const int* __restrict__ kidx3,
                                                    const int* __restrict__ aidx3,
                                                    float* __restrict__ out) {
    long long t = (long long)blockIdx.x * 256 + threadIdx.x;
    if (t >= (long long)B_ * D_ * P_ * R_) return;
    int r = (int)(t % 12);
    int p = (int)((t / 12) % P_);
    int d = (int)((t / (12 * P_)) % D_);
    int b = (int)(t / (12 * (long long)P_ * D_));
    int kk[K_];
    int aa[A_];
#pragma unroll
    for (int k = 0; k < K_; ++k) kk[k] = kidx3[(k * 12 + 0) * 12 + r];
#pragma unroll
    for (int a = 0; a < A_; ++a) aa[a] = aidx3[(0 * 12 + a) * 12 + r];
    float sum = 0.f;
    for (int c = 0; c < C_; ++c) {
        const float* wrow = W + (size_t)(d * C_ + c) * 60;
        const float* xrow = x + ((size_t)(b * C_ + c) * K_) * (P_ * A_) + (size_t)p * A_;
        for (int k = 0; k < K_; ++k) {
            const float* wk = wrow + kk[k] * 12;
            const float* xk = xrow + (size_t)k * (P_ * A_);
#pragma unroll
            for (int a = 0; a < A_; ++a) sum += wk[aa[a]] * xk[a];
        }
    }
    out[t] = sum;
}

extern "C" void kernel_launch(void* const* d_in, const int* in_sizes, int n_in,
                              void* d_out, int out_size, void* d_ws, size_t ws_size,
                              hipStream_t stream) {
    const float* x     = (const float*)d_in[0];
    const float* W     = (const float*)d_in[1];
    const int*   kidx3 = (const int*)d_in[2];
    const int*   aidx3 = (const int*)d_in[3];
    float*       out   = (float*)d_out;

    // new path sizes
    const size_t POOL = (size_t)26 * C_ * 4096 * 12 * 2;  // 327,155,712
    const size_t AB   = (size_t)12 * 80 * 128 * 96 * 2;   //  23,592,960
    const size_t CTH  = (size_t)MT * NT * 2;              //  12,582,912 per slab
    // old path sizes
    const size_t XB = (size_t)NT * KT * 2;                // 167,772,160
    const size_t WB = (size_t)MT * KT * 2;                //  62,914,560

    if (ws_size >= POOL + AB + 4 * CTH) {
        u16* pool = (u16*)d_ws;
        u16* Ab   = (u16*)((char*)d_ws + POOL);
        u16* Ct   = (u16*)((char*)d_ws + POOL + AB);
        poolk<<<dim3(128, 4), 512, 0, stream>>>(x, kidx3, pool);
        abuild<<<5760, 256, 0, stream>>>(W, aidx3, Ab);
        gemmS<<<768, 512, 0, stream>>>(Ab, pool, kidx3, Ct);
        pass4b<4, u16><<<2048, 256, 0, stream>>>(Ct, out);
    } else if (ws_size >= XB + WB + 8 * CTH) {
        u16* Xb = (u16*)d_ws;
        u16* Wb = (u16*)((char*)d_ws + XB);
        u16* Ct = (u16*)((char*)d_ws + XB + WB);
        pass1_xt<<<dim3(4, 128, 4), 256, 0, stream>>>(x, Xb);
        pass2_wb<<<(MT * (KT / 8)) / 256, 256, 0, stream>>>(W, kidx3, aidx3, Wb);
        gemm256<8, u16><<<dim3(96, 8), 512, 0, stream>>>(Wb, Xb, Ct);
        pass4b<8, u16><<<2048, 256, 0, stream>>>(Ct, out);
    } else {
        naive_kernel<<<(B_ * D_ * P_ * R_) / 256, 256, 0, stream>>>(x, W, kidx3, aidx3, out);
    }
}